// Round 1
// baseline (3939.929 us; speedup 1.0000x reference)
//
#include <hip/hip_runtime.h>
#include <math.h>

#define B 4
#define L 4096
#define D 1024
#define H 16
#define DK 64
#define M 256
#define NTOK (B*L)        // 16384
#define NCH 8
#define LC (L/NCH)        // 512

// dn = 64^-0.25 = 2^-1.5 ; dn^2*0.5 = 0.0625 ; ratio = 256^-0.5 = 0.0625
#define DNORM 0.35355339059327373f
#define HALF_DN2 0.0625f
#define RATIO 0.0625f

// ---------------- fp32 tiled GEMM:  C[n][o] = sum_k A[n][k] * W[o][k] ----------------
__global__ __launch_bounds__(256) void gemm_nt128(const float* __restrict__ A,
                                                  const float* __restrict__ W,
                                                  float* __restrict__ C,
                                                  int N, int O, int K) {
    __shared__ float As[8][128];
    __shared__ float Bs[8][128];
    const int t  = threadIdx.x;
    const int tx = t & 15, ty = t >> 4;
    const int lr = t >> 1;
    const int lk = (t & 1) * 4;
    const float* Ab = A + (size_t)(blockIdx.y * 128 + lr) * K + lk;
    const float* Wb = W + (size_t)(blockIdx.x * 128 + lr) * K + lk;
    float acc[8][8];
#pragma unroll
    for (int i = 0; i < 8; i++)
#pragma unroll
        for (int j = 0; j < 8; j++) acc[i][j] = 0.f;

    for (int k0 = 0; k0 < K; k0 += 8) {
        float4 av = *(const float4*)(Ab + k0);
        float4 wv = *(const float4*)(Wb + k0);
        __syncthreads();
        As[lk + 0][lr] = av.x; As[lk + 1][lr] = av.y; As[lk + 2][lr] = av.z; As[lk + 3][lr] = av.w;
        Bs[lk + 0][lr] = wv.x; Bs[lk + 1][lr] = wv.y; Bs[lk + 2][lr] = wv.z; Bs[lk + 3][lr] = wv.w;
        __syncthreads();
#pragma unroll
        for (int kk = 0; kk < 8; kk++) {
            float a[8], b[8];
#pragma unroll
            for (int i = 0; i < 8; i++) a[i] = As[kk][ty * 8 + i];
#pragma unroll
            for (int j = 0; j < 8; j++) b[j] = Bs[kk][tx * 8 + j];
#pragma unroll
            for (int i = 0; i < 8; i++)
#pragma unroll
                for (int j = 0; j < 8; j++) acc[i][j] += a[i] * b[j];
        }
    }
    float* Cb = C + (size_t)(blockIdx.y * 128 + ty * 8) * O + blockIdx.x * 128 + tx * 8;
#pragma unroll
    for (int i = 0; i < 8; i++) {
        float4 o0 = {acc[i][0], acc[i][1], acc[i][2], acc[i][3]};
        float4 o1 = {acc[i][4], acc[i][5], acc[i][6], acc[i][7]};
        *(float4*)(Cb + (size_t)i * O)     = o0;
        *(float4*)(Cb + (size_t)i * O + 4) = o1;
    }
}

// ---------------- fused phi_k + kv/k_sum partial accumulation ----------------
// grid: (NCH, B*H). block 256. Each block: one (b,h), one l-chunk of LC rows.
__global__ __launch_bounds__(256) void kv_kernel(const float* __restrict__ k,
                                                 const float* __restrict__ v,
                                                 const int* __restrict__ mask,
                                                 const float* __restrict__ P,
                                                 float* __restrict__ kvpart,
                                                 float* __restrict__ kspart) {
    const int bh = blockIdx.y;
    const int b  = bh >> 4, h = bh & 15;
    const int ch = blockIdx.x;
    const int t  = threadIdx.x;

    __shared__ float ks_[32][68];
    __shared__ float vs[32][68];
    __shared__ float phis[32][257];
    __shared__ float rmax[32], rnsq[32], rmk[32];

    const int tm = t & 63;   // m base
    const int dg = t >> 6;   // 0..3 -> dk group of 16
    const int lt = t & 31;
    const int mg = t >> 5;   // 0..7 -> m group of 32

    float acc[4][16];
#pragma unroll
    for (int mi = 0; mi < 4; mi++)
#pragma unroll
        for (int j = 0; j < 16; j++) acc[mi][j] = 0.f;
    float ksacc[4] = {0.f, 0.f, 0.f, 0.f};

    for (int tile = 0; tile < LC / 32; ++tile) {
        const int l0 = ch * LC + tile * 32;
        // ---- stage k,v rows (32 x 64) ----
        {
            const int lr = t >> 3;
            const int d0 = (t & 7) * 8;
            const float* ksrc = k + (size_t)(b * L + l0 + lr) * D + h * DK + d0;
            const float* vsrc = v + (size_t)(b * L + l0 + lr) * D + h * DK + d0;
            float4 a0 = *(const float4*)ksrc;
            float4 a1 = *(const float4*)(ksrc + 4);
            float4 b0 = *(const float4*)vsrc;
            float4 b1 = *(const float4*)(vsrc + 4);
            __syncthreads();   // protect previous tile's LDS reads
            *(float4*)&ks_[lr][d0]     = a0;
            *(float4*)&ks_[lr][d0 + 4] = a1;
            *(float4*)&vs[lr][d0]      = b0;
            *(float4*)&vs[lr][d0 + 4]  = b1;
            __syncthreads();
        }
        // ---- projected = dn * (k_row . P_m) ----
        for (int mi = 0; mi < 32; ++mi) {
            const int m = mg * 32 + mi;
            const float4* Pr = (const float4*)(P + m * DK);
            float s = 0.f;
#pragma unroll
            for (int d4 = 0; d4 < 16; ++d4) {
                float4 pv = Pr[d4];
                const float* qr = &ks_[lt][d4 * 4];
                s += pv.x * qr[0] + pv.y * qr[1] + pv.z * qr[2] + pv.w * qr[3];
            }
            phis[lt][m] = DNORM * s;
        }
        __syncthreads();
        // ---- row stats ----
        if (t < 32) {
            float mx = -1e30f;
            for (int m = 0; m < M; m++) mx = fmaxf(mx, phis[t][m]);
            float ns = 0.f;
            for (int d = 0; d < DK; d++) { float kv2 = ks_[t][d]; ns += kv2 * kv2; }
            rmax[t] = mx;
            rnsq[t] = HALF_DN2 * ns;
            rmk[t]  = (float)mask[b * L + l0 + t];
        }
        __syncthreads();
        // ---- transform to phi (with mask) ----
        {
            const float mx = rmax[lt], ns = rnsq[lt], mk = rmk[lt];
            for (int mi = 0; mi < 32; ++mi) {
                const int m = mg * 32 + mi;
                float p = phis[lt][m];
                phis[lt][m] = mk * (RATIO * (__expf(p - mx - ns) + 1e-6f));
            }
        }
        __syncthreads();
        // ---- accumulate kv += phi^T * v ; ksum += sum_l phi ----
        for (int lp = 0; lp < 32; ++lp) {
            float vv[16];
#pragma unroll
            for (int j = 0; j < 16; j++) vv[j] = vs[lp][dg * 16 + j];
#pragma unroll
            for (int mi = 0; mi < 4; mi++) {
                float pm = phis[lp][tm + 64 * mi];
                ksacc[mi] += pm;
#pragma unroll
                for (int j = 0; j < 16; j++) acc[mi][j] += pm * vv[j];
            }
        }
    }
    // ---- write partials ----
    float* kvp = kvpart + ((size_t)ch * 64 + bh) * M * DK;
#pragma unroll
    for (int mi = 0; mi < 4; mi++) {
        const int m = tm + 64 * mi;
#pragma unroll
        for (int j = 0; j < 16; j++) kvp[(size_t)m * DK + dg * 16 + j] = acc[mi][j];
    }
    if (dg == 0) {
        float* ksp = kspart + ((size_t)ch * 64 + bh) * M;
#pragma unroll
        for (int mi = 0; mi < 4; mi++) ksp[tm + 64 * mi] = ksacc[mi];
    }
}

__global__ __launch_bounds__(256) void reduce_kv(const float* __restrict__ kvp,
                                                 float* __restrict__ kvo) {
    const size_t i = (size_t)blockIdx.x * 256 + threadIdx.x;   // < 64*256*64
    float s = 0.f;
    for (int c = 0; c < NCH; c++) s += kvp[(size_t)c * (64 * M * DK) + i];
    kvo[i] = s;
}

__global__ __launch_bounds__(256) void reduce_ks(const float* __restrict__ ksp,
                                                 float* __restrict__ kso) {
    const int i = blockIdx.x * 256 + threadIdx.x;              // < 64*256
    float s = 0.f;
    for (int c = 0; c < NCH; c++) s += ksp[c * (64 * M) + i];
    kso[i] = s;
}

// ---------------- fused phi_q + out + denom + normalize ----------------
// grid: (L/32, B*H). block 256.
__global__ __launch_bounds__(256) void out_kernel(const float* __restrict__ q,
                                                  const float* __restrict__ P,
                                                  const float* __restrict__ kv,
                                                  const float* __restrict__ ksum,
                                                  float* __restrict__ ao) {
    const int bh = blockIdx.y;
    const int b  = bh >> 4, h = bh & 15;
    const int l0 = blockIdx.x * 32;
    const int t  = threadIdx.x;

    __shared__ float qs[32][68];
    __shared__ float phis[32][257];
    __shared__ float rmax[32], rnsq[32], rden[32];

    // ---- stage q rows ----
    {
        const int lr = t >> 3;
        const int d0 = (t & 7) * 8;
        const float* src = q + (size_t)(b * L + l0 + lr) * D + h * DK + d0;
        float4 v0 = *(const float4*)src;
        float4 v1 = *(const float4*)(src + 4);
        *(float4*)&qs[lr][d0]     = v0;
        *(float4*)&qs[lr][d0 + 4] = v1;
    }
    __syncthreads();

    const int lt = t & 31;
    const int mg = t >> 5;
    // ---- projected ----
    for (int mi = 0; mi < 32; ++mi) {
        const int m = mg * 32 + mi;
        const float4* Pr = (const float4*)(P + m * DK);
        float s = 0.f;
#pragma unroll
        for (int d4 = 0; d4 < 16; ++d4) {
            float4 pv = Pr[d4];
            const float* qr = &qs[lt][d4 * 4];
            s += pv.x * qr[0] + pv.y * qr[1] + pv.z * qr[2] + pv.w * qr[3];
        }
        phis[lt][m] = DNORM * s;
    }
    __syncthreads();
    if (t < 32) {
        float mx = -1e30f;
        for (int m = 0; m < M; m++) mx = fmaxf(mx, phis[t][m]);
        float ns = 0.f;
        for (int d = 0; d < DK; d++) { float qv = qs[t][d]; ns += qv * qv; }
        rmax[t] = mx;
        rnsq[t] = HALF_DN2 * ns;
    }
    __syncthreads();
    {
        const float mx = rmax[lt], ns = rnsq[lt];
        for (int mi = 0; mi < 32; ++mi) {
            const int m = mg * 32 + mi;
            float p = phis[lt][m];
            phis[lt][m] = RATIO * (__expf(p - mx - ns) + 1e-6f);
        }
    }
    __syncthreads();
    // ---- out = phi @ kv ; denom = phi . ksum ----
    {
        const int row = t & 31;
        const int dg  = t >> 5;       // 0..7
        const int dk0 = dg * 8;
        float acc[8] = {0.f, 0.f, 0.f, 0.f, 0.f, 0.f, 0.f, 0.f};
        float den = 0.f;
        const float* kvb = kv + (size_t)bh * M * DK + dk0;
        const float* ksb = ksum + bh * M;
        for (int m = 0; m < M; m++) {
            float pm = phis[row][m];
            float4 k0 = *(const float4*)(kvb + (size_t)m * DK);
            float4 k1 = *(const float4*)(kvb + (size_t)m * DK + 4);
            acc[0] += pm * k0.x; acc[1] += pm * k0.y; acc[2] += pm * k0.z; acc[3] += pm * k0.w;
            acc[4] += pm * k1.x; acc[5] += pm * k1.y; acc[6] += pm * k1.z; acc[7] += pm * k1.w;
            den += pm * ksb[m];
        }
        if (dg == 0) rden[row] = den;
        __syncthreads();
        const float inv = 1.f / fmaxf(rden[row], 1e-6f);
        float* dst = ao + (size_t)(b * L + l0 + row) * D + h * DK + dk0;
#pragma unroll
        for (int j = 0; j < 8; j++) dst[j] = acc[j] * inv;
    }
}

extern "C" void kernel_launch(void* const* d_in, const int* in_sizes, int n_in,
                              void* d_out, int out_size, void* d_ws, size_t ws_size,
                              hipStream_t stream) {
    (void)in_sizes; (void)n_in; (void)out_size; (void)ws_size;
    const float* X    = (const float*)d_in[0];
    const int*   mask = (const int*)d_in[1];
    const float* Wq   = (const float*)d_in[2];
    const float* Wk   = (const float*)d_in[3];
    const float* Wv   = (const float*)d_in[4];
    const float* Wo   = (const float*)d_in[5];
    const float* P    = (const float*)d_in[6];

    float* ws     = (float*)d_ws;
    float* buf0   = ws;                 // k, later attn_out       (16,777,216 f)
    float* buf1   = ws + 16777216;      // v, later q              (16,777,216 f)
    float* kvpart = ws + 33554432;      // 8*64*256*64 = 8,388,608 f
    float* kspart = ws + 41943040;      // 8*64*256    =   131,072 f
    float* kv     = ws + 42074112;      // 64*256*64   = 1,048,576 f
    float* ksum   = ws + 43122688;      // 64*256      =    16,384 f
    float* out    = (float*)d_out;

    dim3 gg(8, 128), blk(256);
    // K and V projections
    hipLaunchKernelGGL(gemm_nt128, gg, blk, 0, stream, X, Wk, buf0, NTOK, D, D);
    hipLaunchKernelGGL(gemm_nt128, gg, blk, 0, stream, X, Wv, buf1, NTOK, D, D);
    // kv / k_sum with fused phi_k
    hipLaunchKernelGGL(kv_kernel, dim3(NCH, B * H), blk, 0, stream, buf0, buf1, mask, P, kvpart, kspart);
    hipLaunchKernelGGL(reduce_kv, dim3((64 * M * DK) / 256), blk, 0, stream, kvpart, kv);
    hipLaunchKernelGGL(reduce_ks, dim3((64 * M) / 256), blk, 0, stream, kspart, ksum);
    // Q projection (overwrites v)
    hipLaunchKernelGGL(gemm_nt128, gg, blk, 0, stream, X, Wq, buf1, NTOK, D, D);
    // phi_q + out + normalize (overwrites k)
    hipLaunchKernelGGL(out_kernel, dim3(L / 32, B * H), blk, 0, stream, buf1, P, kv, ksum, buf0);
    // final projection
    hipLaunchKernelGGL(gemm_nt128, gg, blk, 0, stream, buf0, Wo, out, NTOK, D, D);
}

// Round 2
// 2453.014 us; speedup vs baseline: 1.6062x; 1.6062x over previous
//
#include <hip/hip_runtime.h>
#include <math.h>

#define B 4
#define L 4096
#define D 1024
#define H 16
#define DK 64
#define M 256
#define NTOK (B*L)        // 16384
#define NCH 8
#define LC (L/NCH)        // 512

// dn = 64^-0.25 = 2^-1.5 ; dn^2*0.5 = 0.0625 ; ratio = 256^-0.5 = 0.0625
#define DNORM 0.35355339059327373f
#define HALF_DN2 0.0625f
#define RATIO 0.0625f

typedef _Float16 f16x8 __attribute__((ext_vector_type(8)));
typedef float f32x4 __attribute__((ext_vector_type(4)));

__device__ __forceinline__ void gload16(const void* g, void* l) {
    __builtin_amdgcn_global_load_lds((const __attribute__((address_space(1))) unsigned*)g,
                                     (__attribute__((address_space(3))) unsigned*)l, 16, 0, 0);
}

// ---------------- fp32 -> fp16 cast (8 elems/thread) ----------------
__global__ __launch_bounds__(256) void cast_f32_f16(const float* __restrict__ in,
                                                    _Float16* __restrict__ out, int n8) {
    int i = blockIdx.x * 256 + threadIdx.x;
    if (i >= n8) return;
    const float4* p = (const float4*)(in + (size_t)i * 8);
    float4 a = p[0], b = p[1];
    f16x8 o;
    o[0] = (_Float16)a.x; o[1] = (_Float16)a.y; o[2] = (_Float16)a.z; o[3] = (_Float16)a.w;
    o[4] = (_Float16)b.x; o[5] = (_Float16)b.y; o[6] = (_Float16)b.z; o[7] = (_Float16)b.w;
    *(f16x8*)(out + (size_t)i * 8) = o;
}

// ---------------- fp16 MFMA GEMM:  C[n][o] = sum_k A[n][k] * W[o][k] ----------------
// 128x128 tile, BK=32, 4 waves (2x2 of 64x64), mfma_f32_16x16x32_f16, fp32 accum.
template <typename CT>
__global__ __launch_bounds__(256) void gemm_f16(const _Float16* __restrict__ A,
                                                const _Float16* __restrict__ W,
                                                CT* __restrict__ C,
                                                int N, int K) {
    __shared__ _Float16 As[128 * 32];
    __shared__ _Float16 Bs[128 * 32];
    const int t    = threadIdx.x;
    const int lane = t & 63;
    const int w    = t >> 6;
    const int wr   = w >> 1, wc = w & 1;
    const int brow = blockIdx.y * 128, bcol = blockIdx.x * 128;

    // staging: chunk c (16B = 8 halfs): row = c>>2, koff = (c&3)*8. c0 = t covers 0..255.
    const int c0 = t, c1 = t + 256;
    const _Float16* Ag0 = A + (size_t)(brow + (c0 >> 2)) * K + (c0 & 3) * 8;
    const _Float16* Ag1 = A + (size_t)(brow + (c1 >> 2)) * K + (c1 & 3) * 8;
    const _Float16* Wg0 = W + (size_t)(bcol + (c0 >> 2)) * K + (c0 & 3) * 8;
    const _Float16* Wg1 = W + (size_t)(bcol + (c1 >> 2)) * K + (c1 & 3) * 8;
    _Float16* Al0 = As + c0 * 8;
    _Float16* Al1 = As + c1 * 8;
    _Float16* Bl0 = Bs + c0 * 8;
    _Float16* Bl1 = Bs + c1 * 8;

    f32x4 acc[4][4];
#pragma unroll
    for (int i = 0; i < 4; i++)
#pragma unroll
        for (int j = 0; j < 4; j++) acc[i][j] = (f32x4){0.f, 0.f, 0.f, 0.f};

    const int fr = lane & 15;    // fragment row/col within 16
    const int kq = lane >> 4;    // 0..3 -> k-quarter
    const int aoff = (wr * 64 + fr) * 32 + kq * 8;
    const int boff = (wc * 64 + fr) * 32 + kq * 8;

    for (int k0 = 0; k0 < K; k0 += 32) {
        __syncthreads();
        gload16(Ag0 + k0, Al0);
        gload16(Ag1 + k0, Al1);
        gload16(Wg0 + k0, Bl0);
        gload16(Wg1 + k0, Bl1);
        __syncthreads();
        f16x8 af[4], bf[4];
#pragma unroll
        for (int mi = 0; mi < 4; mi++) af[mi] = *(const f16x8*)&As[aoff + mi * 512];
#pragma unroll
        for (int ni = 0; ni < 4; ni++) bf[ni] = *(const f16x8*)&Bs[boff + ni * 512];
#pragma unroll
        for (int mi = 0; mi < 4; mi++)
#pragma unroll
            for (int ni = 0; ni < 4; ni++)
                acc[mi][ni] = __builtin_amdgcn_mfma_f32_16x16x32_f16(af[mi], bf[ni], acc[mi][ni], 0, 0, 0);
    }
    // C/D layout: col = lane&15, row = (lane>>4)*4 + reg
#pragma unroll
    for (int mi = 0; mi < 4; mi++) {
#pragma unroll
        for (int ni = 0; ni < 4; ni++) {
            const int row = brow + wr * 64 + mi * 16 + kq * 4;
            const int col = bcol + wc * 64 + ni * 16 + fr;
#pragma unroll
            for (int r = 0; r < 4; r++)
                C[(size_t)(row + r) * N + col] = (CT)acc[mi][ni][r];
        }
    }
}

// ---------------- fused phi_k + kv/k_sum partial accumulation ----------------
__global__ __launch_bounds__(256) void kv_kernel(const _Float16* __restrict__ k,
                                                 const _Float16* __restrict__ v,
                                                 const int* __restrict__ mask,
                                                 const float* __restrict__ P,
                                                 float* __restrict__ kvpart,
                                                 float* __restrict__ kspart) {
    const int bh = blockIdx.y;
    const int b  = bh >> 4, h = bh & 15;
    const int ch = blockIdx.x;
    const int t  = threadIdx.x;

    __shared__ float ks_[32][68];
    __shared__ float vs[32][68];
    __shared__ float phis[32][257];
    __shared__ float rmax[32], rnsq[32], rmk[32];

    const int tm = t & 63;
    const int dg = t >> 6;
    const int lt = t & 31;
    const int mg = t >> 5;

    float acc[4][16];
#pragma unroll
    for (int mi = 0; mi < 4; mi++)
#pragma unroll
        for (int j = 0; j < 16; j++) acc[mi][j] = 0.f;
    float ksacc[4] = {0.f, 0.f, 0.f, 0.f};

    for (int tile = 0; tile < LC / 32; ++tile) {
        const int l0 = ch * LC + tile * 32;
        {
            const int lr = t >> 3;
            const int d0 = (t & 7) * 8;
            const _Float16* ksrc = k + (size_t)(b * L + l0 + lr) * D + h * DK + d0;
            const _Float16* vsrc = v + (size_t)(b * L + l0 + lr) * D + h * DK + d0;
            f16x8 ak = *(const f16x8*)ksrc;
            f16x8 av = *(const f16x8*)vsrc;
            __syncthreads();   // protect previous tile's LDS reads
#pragma unroll
            for (int j = 0; j < 8; j++) {
                ks_[lr][d0 + j] = (float)ak[j];
                vs[lr][d0 + j]  = (float)av[j];
            }
            __syncthreads();
        }
        for (int mi = 0; mi < 32; ++mi) {
            const int m = mg * 32 + mi;
            const float4* Pr = (const float4*)(P + m * DK);
            float s = 0.f;
#pragma unroll
            for (int d4 = 0; d4 < 16; ++d4) {
                float4 pv = Pr[d4];
                const float* qr = &ks_[lt][d4 * 4];
                s += pv.x * qr[0] + pv.y * qr[1] + pv.z * qr[2] + pv.w * qr[3];
            }
            phis[lt][m] = DNORM * s;
        }
        __syncthreads();
        if (t < 32) {
            float mx = -1e30f;
            for (int m = 0; m < M; m++) mx = fmaxf(mx, phis[t][m]);
            float ns = 0.f;
            for (int d = 0; d < DK; d++) { float kv2 = ks_[t][d]; ns += kv2 * kv2; }
            rmax[t] = mx;
            rnsq[t] = HALF_DN2 * ns;
            rmk[t]  = (float)mask[b * L + l0 + t];
        }
        __syncthreads();
        {
            const float mx = rmax[lt], ns = rnsq[lt], mk = rmk[lt];
            for (int mi = 0; mi < 32; ++mi) {
                const int m = mg * 32 + mi;
                float p = phis[lt][m];
                phis[lt][m] = mk * (RATIO * (__expf(p - mx - ns) + 1e-6f));
            }
        }
        __syncthreads();
        for (int lp = 0; lp < 32; ++lp) {
            float vv[16];
#pragma unroll
            for (int j = 0; j < 16; j++) vv[j] = vs[lp][dg * 16 + j];
#pragma unroll
            for (int mi = 0; mi < 4; mi++) {
                float pm = phis[lp][tm + 64 * mi];
                ksacc[mi] += pm;
#pragma unroll
                for (int j = 0; j < 16; j++) acc[mi][j] += pm * vv[j];
            }
        }
    }
    float* kvp = kvpart + ((size_t)ch * 64 + bh) * M * DK;
#pragma unroll
    for (int mi = 0; mi < 4; mi++) {
        const int m = tm + 64 * mi;
#pragma unroll
        for (int j = 0; j < 16; j++) kvp[(size_t)m * DK + dg * 16 + j] = acc[mi][j];
    }
    if (dg == 0) {
        float* ksp = kspart + ((size_t)ch * 64 + bh) * M;
#pragma unroll
        for (int mi = 0; mi < 4; mi++) ksp[tm + 64 * mi] = ksacc[mi];
    }
}

__global__ __launch_bounds__(256) void reduce_kv(const float* __restrict__ kvp,
                                                 float* __restrict__ kvo) {
    const size_t i = (size_t)blockIdx.x * 256 + threadIdx.x;
    float s = 0.f;
    for (int c = 0; c < NCH; c++) s += kvp[(size_t)c * (64 * M * DK) + i];
    kvo[i] = s;
}

__global__ __launch_bounds__(256) void reduce_ks(const float* __restrict__ ksp,
                                                 float* __restrict__ kso) {
    const int i = blockIdx.x * 256 + threadIdx.x;
    float s = 0.f;
    for (int c = 0; c < NCH; c++) s += ksp[c * (64 * M) + i];
    kso[i] = s;
}

// ---------------- fused phi_q + out + denom + normalize (fp16 in/out) ----------------
__global__ __launch_bounds__(256) void out_kernel(const _Float16* __restrict__ q,
                                                  const float* __restrict__ P,
                                                  const float* __restrict__ kv,
                                                  const float* __restrict__ ksum,
                                                  _Float16* __restrict__ ao) {
    const int bh = blockIdx.y;
    const int b  = bh >> 4, h = bh & 15;
    const int l0 = blockIdx.x * 32;
    const int t  = threadIdx.x;

    __shared__ float qs[32][68];
    __shared__ float phis[32][257];
    __shared__ float rmax[32], rnsq[32], rden[32];

    {
        const int lr = t >> 3;
        const int d0 = (t & 7) * 8;
        const _Float16* src = q + (size_t)(b * L + l0 + lr) * D + h * DK + d0;
        f16x8 a = *(const f16x8*)src;
#pragma unroll
        for (int j = 0; j < 8; j++) qs[lr][d0 + j] = (float)a[j];
    }
    __syncthreads();

    const int lt = t & 31;
    const int mg = t >> 5;
    for (int mi = 0; mi < 32; ++mi) {
        const int m = mg * 32 + mi;
        const float4* Pr = (const float4*)(P + m * DK);
        float s = 0.f;
#pragma unroll
        for (int d4 = 0; d4 < 16; ++d4) {
            float4 pv = Pr[d4];
            const float* qr = &qs[lt][d4 * 4];
            s += pv.x * qr[0] + pv.y * qr[1] + pv.z * qr[2] + pv.w * qr[3];
        }
        phis[lt][m] = DNORM * s;
    }
    __syncthreads();
    if (t < 32) {
        float mx = -1e30f;
        for (int m = 0; m < M; m++) mx = fmaxf(mx, phis[t][m]);
        float ns = 0.f;
        for (int d = 0; d < DK; d++) { float qv = qs[t][d]; ns += qv * qv; }
        rmax[t] = mx;
        rnsq[t] = HALF_DN2 * ns;
    }
    __syncthreads();
    {
        const float mx = rmax[lt], ns = rnsq[lt];
        for (int mi = 0; mi < 32; ++mi) {
            const int m = mg * 32 + mi;
            float p = phis[lt][m];
            phis[lt][m] = RATIO * (__expf(p - mx - ns) + 1e-6f);
        }
    }
    __syncthreads();
    {
        const int row = t & 31;
        const int dg  = t >> 5;
        const int dk0 = dg * 8;
        float acc[8] = {0.f, 0.f, 0.f, 0.f, 0.f, 0.f, 0.f, 0.f};
        float den = 0.f;
        const float* kvb = kv + (size_t)bh * M * DK + dk0;
        const float* ksb = ksum + bh * M;
        for (int m = 0; m < M; m++) {
            float pm = phis[row][m];
            float4 k0 = *(const float4*)(kvb + (size_t)m * DK);
            float4 k1 = *(const float4*)(kvb + (size_t)m * DK + 4);
            acc[0] += pm * k0.x; acc[1] += pm * k0.y; acc[2] += pm * k0.z; acc[3] += pm * k0.w;
            acc[4] += pm * k1.x; acc[5] += pm * k1.y; acc[6] += pm * k1.z; acc[7] += pm * k1.w;
            den += pm * ksb[m];
        }
        if (dg == 0) rden[row] = den;
        __syncthreads();
        const float inv = 1.f / fmaxf(rden[row], 1e-6f);
        _Float16* dst = ao + (size_t)(b * L + l0 + row) * D + h * DK + dk0;
        f16x8 o;
#pragma unroll
        for (int j = 0; j < 8; j++) o[j] = (_Float16)(acc[j] * inv);
        *(f16x8*)dst = o;
    }
}

extern "C" void kernel_launch(void* const* d_in, const int* in_sizes, int n_in,
                              void* d_out, int out_size, void* d_ws, size_t ws_size,
                              hipStream_t stream) {
    (void)in_sizes; (void)n_in; (void)out_size; (void)ws_size;
    const float* X    = (const float*)d_in[0];
    const int*   mask = (const int*)d_in[1];
    const float* Wq   = (const float*)d_in[2];
    const float* Wk   = (const float*)d_in[3];
    const float* Wv   = (const float*)d_in[4];
    const float* Wo   = (const float*)d_in[5];
    const float* P    = (const float*)d_in[6];

    char* ws = (char*)d_ws;
    _Float16* bufK  = (_Float16*)ws;                      // k, later attn (32MB)
    _Float16* bufVQ = (_Float16*)(ws + 33554432);         // v, later q    (32MB)
    float* kvpart   = (float*)(ws + 67108864);            // 32MB
    float* kspart   = (float*)(ws + 100663296);           // 512KB
    float* kv       = (float*)(ws + 101187584);           // 4MB
    float* ksum     = (float*)(ws + 105381888);           // 64KB
    _Float16* Xh    = (_Float16*)(ws + 105447424);        // 32MB
    _Float16* Wkh   = (_Float16*)(ws + 139001856);        // 2MB
    _Float16* Wvh   = (_Float16*)(ws + 141099008);        // 2MB
    _Float16* Wqh   = (_Float16*)(ws + 143196160);        // 2MB
    _Float16* Woh   = (_Float16*)(ws + 145293312);        // 2MB -> total ~147.4MB
    float* out      = (float*)d_out;

    dim3 blk(256);
    // casts
    hipLaunchKernelGGL(cast_f32_f16, dim3(8192), blk, 0, stream, X, Xh, 2097152);
    hipLaunchKernelGGL(cast_f32_f16, dim3(512), blk, 0, stream, Wk, Wkh, 131072);
    hipLaunchKernelGGL(cast_f32_f16, dim3(512), blk, 0, stream, Wv, Wvh, 131072);
    hipLaunchKernelGGL(cast_f32_f16, dim3(512), blk, 0, stream, Wq, Wqh, 131072);
    hipLaunchKernelGGL(cast_f32_f16, dim3(512), blk, 0, stream, Wo, Woh, 131072);

    dim3 gg(8, 128);
    // K and V projections (fp16 out)
    hipLaunchKernelGGL((gemm_f16<_Float16>), gg, blk, 0, stream, Xh, Wkh, bufK, D, D);
    hipLaunchKernelGGL((gemm_f16<_Float16>), gg, blk, 0, stream, Xh, Wvh, bufVQ, D, D);
    // kv / k_sum with fused phi_k
    hipLaunchKernelGGL(kv_kernel, dim3(NCH, B * H), blk, 0, stream, bufK, bufVQ, mask, P, kvpart, kspart);
    hipLaunchKernelGGL(reduce_kv, dim3((64 * M * DK) / 256), blk, 0, stream, kvpart, kv);
    hipLaunchKernelGGL(reduce_ks, dim3((64 * M) / 256), blk, 0, stream, kspart, ksum);
    // Q projection (overwrites v)
    hipLaunchKernelGGL((gemm_f16<_Float16>), gg, blk, 0, stream, Xh, Wqh, bufVQ, D, D);
    // phi_q + out + normalize (overwrites k, fp16 out)
    hipLaunchKernelGGL(out_kernel, dim3(L / 32, B * H), blk, 0, stream, bufVQ, P, kv, ksum, bufK);
    // final projection (fp32 out)
    hipLaunchKernelGGL((gemm_f16<float>), gg, blk, 0, stream, bufK, Woh, out, D, D);
}

// Round 3
// 1438.473 us; speedup vs baseline: 2.7390x; 1.7053x over previous
//
#include <hip/hip_runtime.h>
#include <math.h>

#define B 4
#define L 4096
#define D 1024
#define H 16
#define DK 64
#define M 256
#define NTOK (B*L)        // 16384
#define NCH 8
#define LC (L/NCH)        // 512

// dn = 64^-0.25 = 2^-1.5 ; dn^2*0.5 = 0.0625 ; ratio = 256^-0.5 = 0.0625
#define DNORM 0.35355339059327373f
#define HALF_DN2 0.0625f
#define RATIO 0.0625f

typedef _Float16 f16x8 __attribute__((ext_vector_type(8)));
typedef float f32x4 __attribute__((ext_vector_type(4)));

__device__ __forceinline__ void gload16(const void* g, void* l) {
    __builtin_amdgcn_global_load_lds((const __attribute__((address_space(1))) unsigned*)g,
                                     (__attribute__((address_space(3))) unsigned*)l, 16, 0, 0);
}

// ---------------- fp32 -> fp16 cast (8 elems/thread) ----------------
__global__ __launch_bounds__(256) void cast_f32_f16(const float* __restrict__ in,
                                                    _Float16* __restrict__ out, int n8) {
    int i = blockIdx.x * 256 + threadIdx.x;
    if (i >= n8) return;
    const float4* p = (const float4*)(in + (size_t)i * 8);
    float4 a = p[0], b = p[1];
    f16x8 o;
    o[0] = (_Float16)a.x; o[1] = (_Float16)a.y; o[2] = (_Float16)a.z; o[3] = (_Float16)a.w;
    o[4] = (_Float16)b.x; o[5] = (_Float16)b.y; o[6] = (_Float16)b.z; o[7] = (_Float16)b.w;
    *(f16x8*)(out + (size_t)i * 8) = o;
}

// ---------------- fp16 MFMA GEMM:  C[n][o] = sum_k A[n][k] * W[o][k] ----------------
template <typename CT>
__global__ __launch_bounds__(256) void gemm_f16(const _Float16* __restrict__ A,
                                                const _Float16* __restrict__ W,
                                                CT* __restrict__ C,
                                                int N, int K) {
    __shared__ _Float16 As[128 * 32];
    __shared__ _Float16 Bs[128 * 32];
    const int t    = threadIdx.x;
    const int lane = t & 63;
    const int w    = t >> 6;
    const int wr   = w >> 1, wc = w & 1;
    const int brow = blockIdx.y * 128, bcol = blockIdx.x * 128;

    const int c0 = t, c1 = t + 256;
    const _Float16* Ag0 = A + (size_t)(brow + (c0 >> 2)) * K + (c0 & 3) * 8;
    const _Float16* Ag1 = A + (size_t)(brow + (c1 >> 2)) * K + (c1 & 3) * 8;
    const _Float16* Wg0 = W + (size_t)(bcol + (c0 >> 2)) * K + (c0 & 3) * 8;
    const _Float16* Wg1 = W + (size_t)(bcol + (c1 >> 2)) * K + (c1 & 3) * 8;
    _Float16* Al0 = As + c0 * 8;
    _Float16* Al1 = As + c1 * 8;
    _Float16* Bl0 = Bs + c0 * 8;
    _Float16* Bl1 = Bs + c1 * 8;

    f32x4 acc[4][4];
#pragma unroll
    for (int i = 0; i < 4; i++)
#pragma unroll
        for (int j = 0; j < 4; j++) acc[i][j] = (f32x4){0.f, 0.f, 0.f, 0.f};

    const int fr = lane & 15;
    const int kq = lane >> 4;
    const int aoff = (wr * 64 + fr) * 32 + kq * 8;
    const int boff = (wc * 64 + fr) * 32 + kq * 8;

    for (int k0 = 0; k0 < K; k0 += 32) {
        __syncthreads();
        gload16(Ag0 + k0, Al0);
        gload16(Ag1 + k0, Al1);
        gload16(Wg0 + k0, Bl0);
        gload16(Wg1 + k0, Bl1);
        __syncthreads();
        f16x8 af[4], bf[4];
#pragma unroll
        for (int mi = 0; mi < 4; mi++) af[mi] = *(const f16x8*)&As[aoff + mi * 512];
#pragma unroll
        for (int ni = 0; ni < 4; ni++) bf[ni] = *(const f16x8*)&Bs[boff + ni * 512];
#pragma unroll
        for (int mi = 0; mi < 4; mi++)
#pragma unroll
            for (int ni = 0; ni < 4; ni++)
                acc[mi][ni] = __builtin_amdgcn_mfma_f32_16x16x32_f16(af[mi], bf[ni], acc[mi][ni], 0, 0, 0);
    }
#pragma unroll
    for (int mi = 0; mi < 4; mi++) {
#pragma unroll
        for (int ni = 0; ni < 4; ni++) {
            const int row = brow + wr * 64 + mi * 16 + kq * 4;
            const int col = bcol + wc * 64 + ni * 16 + fr;
#pragma unroll
            for (int r = 0; r < 4; r++)
                C[(size_t)(row + r) * N + col] = (CT)acc[mi][ni][r];
        }
    }
}

// ---------------- fused phi_k + kv/k_sum partial accumulation ----------------
__global__ __launch_bounds__(256) void kv_kernel(const _Float16* __restrict__ k,
                                                 const _Float16* __restrict__ v,
                                                 const int* __restrict__ mask,
                                                 const float* __restrict__ P,
                                                 float* __restrict__ kvpart,
                                                 float* __restrict__ kspart) {
    const int bh = blockIdx.y;
    const int b  = bh >> 4, h = bh & 15;
    const int ch = blockIdx.x;
    const int t  = threadIdx.x;

    __shared__ float ks_[32][68];
    __shared__ float vs[32][68];
    __shared__ float phis[32][257];
    __shared__ float rmax[32], rnsq[32], rmk[32];

    const int tm = t & 63;
    const int dg = t >> 6;
    const int lt = t & 31;
    const int mg = t >> 5;

    float acc[4][16];
#pragma unroll
    for (int mi = 0; mi < 4; mi++)
#pragma unroll
        for (int j = 0; j < 16; j++) acc[mi][j] = 0.f;
    float ksacc[4] = {0.f, 0.f, 0.f, 0.f};

    for (int tile = 0; tile < LC / 32; ++tile) {
        const int l0 = ch * LC + tile * 32;
        {
            const int lr = t >> 3;
            const int d0 = (t & 7) * 8;
            const _Float16* ksrc = k + (size_t)(b * L + l0 + lr) * D + h * DK + d0;
            const _Float16* vsrc = v + (size_t)(b * L + l0 + lr) * D + h * DK + d0;
            f16x8 ak = *(const f16x8*)ksrc;
            f16x8 av = *(const f16x8*)vsrc;
            __syncthreads();
#pragma unroll
            for (int j = 0; j < 8; j++) {
                ks_[lr][d0 + j] = (float)ak[j];
                vs[lr][d0 + j]  = (float)av[j];
            }
            __syncthreads();
        }
        for (int mi = 0; mi < 32; ++mi) {
            const int m = mg * 32 + mi;
            const float4* Pr = (const float4*)(P + m * DK);
            float s = 0.f;
#pragma unroll
            for (int d4 = 0; d4 < 16; ++d4) {
                float4 pv = Pr[d4];
                const float* qr = &ks_[lt][d4 * 4];
                s += pv.x * qr[0] + pv.y * qr[1] + pv.z * qr[2] + pv.w * qr[3];
            }
            phis[lt][m] = DNORM * s;
        }
        __syncthreads();
        if (t < 32) {
            float mx = -1e30f;
            for (int m = 0; m < M; m++) mx = fmaxf(mx, phis[t][m]);
            float ns = 0.f;
            for (int d = 0; d < DK; d++) { float kv2 = ks_[t][d]; ns += kv2 * kv2; }
            rmax[t] = mx;
            rnsq[t] = HALF_DN2 * ns;
            rmk[t]  = (float)mask[b * L + l0 + t];
        }
        __syncthreads();
        {
            const float mx = rmax[lt], ns = rnsq[lt], mk = rmk[lt];
            for (int mi = 0; mi < 32; ++mi) {
                const int m = mg * 32 + mi;
                float p = phis[lt][m];
                phis[lt][m] = mk * (RATIO * (__expf(p - mx - ns) + 1e-6f));
            }
        }
        __syncthreads();
        for (int lp = 0; lp < 32; ++lp) {
            float vv[16];
#pragma unroll
            for (int j = 0; j < 16; j++) vv[j] = vs[lp][dg * 16 + j];
#pragma unroll
            for (int mi = 0; mi < 4; mi++) {
                float pm = phis[lp][tm + 64 * mi];
                ksacc[mi] += pm;
#pragma unroll
                for (int j = 0; j < 16; j++) acc[mi][j] += pm * vv[j];
            }
        }
    }
    float* kvp = kvpart + ((size_t)ch * 64 + bh) * M * DK;
#pragma unroll
    for (int mi = 0; mi < 4; mi++) {
        const int m = tm + 64 * mi;
#pragma unroll
        for (int j = 0; j < 16; j++) kvp[(size_t)m * DK + dg * 16 + j] = acc[mi][j];
    }
    if (dg == 0) {
        float* ksp = kspart + ((size_t)ch * 64 + bh) * M;
#pragma unroll
        for (int mi = 0; mi < 4; mi++) ksp[tm + 64 * mi] = ksacc[mi];
    }
}

// ---------------- reduce partials -> kvt fp16 [bh][80][256] (col 64 = ksum, 65..79 = 0) ----------------
__global__ __launch_bounds__(256) void reduce_kvt(const float* __restrict__ kvp,
                                                  const float* __restrict__ ksp,
                                                  _Float16* __restrict__ kvt) {
    const int bh = blockIdx.x;
    const int t  = threadIdx.x;   // m index
    float s[64];
#pragma unroll
    for (int c = 0; c < 64; c++) s[c] = 0.f;
    float s64 = 0.f;
    for (int ch = 0; ch < NCH; ch++) {
        const float* src = kvp + (((size_t)ch * 64 + bh) * M + t) * DK;
#pragma unroll
        for (int c4 = 0; c4 < 16; c4++) {
            float4 v = *(const float4*)(src + c4 * 4);
            s[c4 * 4 + 0] += v.x; s[c4 * 4 + 1] += v.y;
            s[c4 * 4 + 2] += v.z; s[c4 * 4 + 3] += v.w;
        }
        s64 += ksp[((size_t)ch * 64 + bh) * M + t];
    }
    _Float16* dst = kvt + (size_t)bh * 80 * 256;
#pragma unroll
    for (int c = 0; c < 64; c++) dst[c * 256 + t] = (_Float16)s[c];
    dst[64 * 256 + t] = (_Float16)s64;
#pragma unroll
    for (int c = 65; c < 80; c++) dst[c * 256 + t] = (_Float16)0.f;
}

// ---------------- fused phi_q + out + denom + normalize, MFMA ----------------
// grid (L/64, B*H), block 256 (4 waves). Each wave owns 16 rows.
__global__ __launch_bounds__(256) void out_kernel2(const _Float16* __restrict__ q,
                                                   const _Float16* __restrict__ Ph,
                                                   const _Float16* __restrict__ kvt,
                                                   _Float16* __restrict__ ao) {
    const int bh = blockIdx.y, b = bh >> 4, h = bh & 15;
    const int l0 = blockIdx.x * 64;
    const int t = threadIdx.x, lane = t & 63, w = t >> 6;
    const int fr = lane & 15, kq = lane >> 4;

    __shared__ _Float16 qs[64 * 72];
    __shared__ _Float16 phis[64 * 264];
    __shared__ float rnsq[64];

    // ---- stage q tile + row norms ----
    {
        const int row = t >> 2, seg = t & 3;
        const _Float16* src = q + (size_t)(b * L + l0 + row) * D + h * DK + seg * 16;
        f16x8 a0 = *(const f16x8*)src;
        f16x8 a1 = *(const f16x8*)(src + 8);
        *(f16x8*)&qs[row * 72 + seg * 16] = a0;
        *(f16x8*)&qs[row * 72 + seg * 16 + 8] = a1;
        float ns = 0.f;
#pragma unroll
        for (int j = 0; j < 8; j++)
            ns += (float)a0[j] * (float)a0[j] + (float)a1[j] * (float)a1[j];
        ns += __shfl_xor(ns, 1);
        ns += __shfl_xor(ns, 2);
        if (seg == 0) rnsq[row] = ns * HALF_DN2;
    }
    __syncthreads();

    // ---- phase 1: proj[64][256] = q @ P^T ----
    f16x8 aq0 = *(const f16x8*)&qs[(w * 16 + fr) * 72 + kq * 8];
    f16x8 aq1 = *(const f16x8*)&qs[(w * 16 + fr) * 72 + kq * 8 + 32];
    f32x4 pr[16];
#pragma unroll
    for (int nf = 0; nf < 16; nf++) {
        const _Float16* pb = Ph + (nf * 16 + fr) * 64 + kq * 8;
        f16x8 b0 = *(const f16x8*)pb;
        f16x8 b1 = *(const f16x8*)(pb + 32);
        f32x4 c = {0.f, 0.f, 0.f, 0.f};
        c = __builtin_amdgcn_mfma_f32_16x16x32_f16(aq0, b0, c, 0, 0, 0);
        c = __builtin_amdgcn_mfma_f32_16x16x32_f16(aq1, b1, c, 0, 0, 0);
        pr[nf] = c;
    }
    // ---- row max (C layout: col=fr of frag nf, row = kq*4+r within wave's 16) ----
    float mx[4] = {-1e30f, -1e30f, -1e30f, -1e30f};
#pragma unroll
    for (int nf = 0; nf < 16; nf++)
#pragma unroll
        for (int r = 0; r < 4; r++) {
            pr[nf][r] *= DNORM;
            mx[r] = fmaxf(mx[r], pr[nf][r]);
        }
#pragma unroll
    for (int r = 0; r < 4; r++) {
        mx[r] = fmaxf(mx[r], __shfl_xor(mx[r], 1));
        mx[r] = fmaxf(mx[r], __shfl_xor(mx[r], 2));
        mx[r] = fmaxf(mx[r], __shfl_xor(mx[r], 4));
        mx[r] = fmaxf(mx[r], __shfl_xor(mx[r], 8));
    }
    float sub[4];
#pragma unroll
    for (int r = 0; r < 4; r++) sub[r] = mx[r] + rnsq[w * 16 + kq * 4 + r];
    // ---- phi -> LDS fp16 ----
#pragma unroll
    for (int nf = 0; nf < 16; nf++)
#pragma unroll
        for (int r = 0; r < 4; r++) {
            float val = RATIO * (__expf(pr[nf][r] - sub[r]) + 1e-6f);
            phis[(w * 16 + kq * 4 + r) * 264 + nf * 16 + fr] = (_Float16)val;
        }
    __syncthreads();

    // ---- phase 2: out[64][80] = phi @ kvt^T (col 64 = denom) ----
    f32x4 acc[5];
#pragma unroll
    for (int n2 = 0; n2 < 5; n2++) acc[n2] = (f32x4){0.f, 0.f, 0.f, 0.f};
    const _Float16* kvb = kvt + (size_t)bh * 80 * 256;
#pragma unroll
    for (int ks = 0; ks < 8; ks++) {
        f16x8 af = *(const f16x8*)&phis[(w * 16 + fr) * 264 + kq * 8 + ks * 32];
#pragma unroll
        for (int n2 = 0; n2 < 5; n2++) {
            f16x8 bf = *(const f16x8*)&kvb[(n2 * 16 + fr) * 256 + kq * 8 + ks * 32];
            acc[n2] = __builtin_amdgcn_mfma_f32_16x16x32_f16(af, bf, acc[n2], 0, 0, 0);
        }
    }
    // ---- normalize + write ----
#pragma unroll
    for (int r = 0; r < 4; r++) {
        float den = __shfl(acc[4][r], (lane & 48));   // lane with fr==0 holds col 64
        float inv = 1.f / fmaxf(den, 1e-6f);
        const int row = l0 + w * 16 + kq * 4 + r;
        _Float16* dst = ao + (size_t)(b * L + row) * D + h * DK;
#pragma unroll
        for (int n2 = 0; n2 < 4; n2++)
            dst[n2 * 16 + fr] = (_Float16)(acc[n2][r] * inv);
    }
}

extern "C" void kernel_launch(void* const* d_in, const int* in_sizes, int n_in,
                              void* d_out, int out_size, void* d_ws, size_t ws_size,
                              hipStream_t stream) {
    (void)in_sizes; (void)n_in; (void)out_size; (void)ws_size;
    const float* X    = (const float*)d_in[0];
    const int*   mask = (const int*)d_in[1];
    const float* Wq   = (const float*)d_in[2];
    const float* Wk   = (const float*)d_in[3];
    const float* Wv   = (const float*)d_in[4];
    const float* Wo   = (const float*)d_in[5];
    const float* P    = (const float*)d_in[6];

    char* ws = (char*)d_ws;
    _Float16* bufK  = (_Float16*)ws;                      // k, later attn (32MB)
    _Float16* bufVQ = (_Float16*)(ws + 33554432);         // v, later q    (32MB)
    float* kvpart   = (float*)(ws + 67108864);            // 32MB
    float* kspart   = (float*)(ws + 100663296);           // 512KB
    _Float16* kvt   = (_Float16*)(ws + 101187584);        // 2.62MB
    _Float16* Xh    = (_Float16*)(ws + 103809024);        // 32MB
    _Float16* Wkh   = (_Float16*)(ws + 137363456);        // 2MB
    _Float16* Wvh   = (_Float16*)(ws + 139460608);        // 2MB
    _Float16* Wqh   = (_Float16*)(ws + 141557760);        // 2MB
    _Float16* Woh   = (_Float16*)(ws + 143654912);        // 2MB
    _Float16* Ph    = (_Float16*)(ws + 145752064);        // 32KB -> ~145.8MB total
    float* out      = (float*)d_out;

    dim3 blk(256);
    hipLaunchKernelGGL(cast_f32_f16, dim3(8192), blk, 0, stream, X, Xh, 2097152);
    hipLaunchKernelGGL(cast_f32_f16, dim3(512), blk, 0, stream, Wk, Wkh, 131072);
    hipLaunchKernelGGL(cast_f32_f16, dim3(512), blk, 0, stream, Wv, Wvh, 131072);
    hipLaunchKernelGGL(cast_f32_f16, dim3(512), blk, 0, stream, Wq, Wqh, 131072);
    hipLaunchKernelGGL(cast_f32_f16, dim3(512), blk, 0, stream, Wo, Woh, 131072);
    hipLaunchKernelGGL(cast_f32_f16, dim3(8), blk, 0, stream, P, Ph, 2048);

    dim3 gg(8, 128);
    hipLaunchKernelGGL((gemm_f16<_Float16>), gg, blk, 0, stream, Xh, Wkh, bufK, D, D);
    hipLaunchKernelGGL((gemm_f16<_Float16>), gg, blk, 0, stream, Xh, Wvh, bufVQ, D, D);
    hipLaunchKernelGGL(kv_kernel, dim3(NCH, B * H), blk, 0, stream, bufK, bufVQ, mask, P, kvpart, kspart);
    hipLaunchKernelGGL(reduce_kvt, dim3(64), blk, 0, stream, kvpart, kspart, kvt);
    hipLaunchKernelGGL((gemm_f16<_Float16>), gg, blk, 0, stream, Xh, Wqh, bufVQ, D, D);
    hipLaunchKernelGGL(out_kernel2, dim3(L / 64, B * H), blk, 0, stream, bufVQ, Ph, kvt, bufK);
    hipLaunchKernelGGL((gemm_f16<float>), gg, blk, 0, stream, bufK, Woh, out, D, D);
}

// Round 4
// 495.668 us; speedup vs baseline: 7.9487x; 2.9021x over previous
//
#include <hip/hip_runtime.h>
#include <math.h>

#define B 4
#define L 4096
#define D 1024
#define H 16
#define DK 64
#define M 256
#define NTOK (B*L)        // 16384
#define NCH 8
#define LC (L/NCH)        // 512

// dn = 64^-0.25 = 2^-1.5 ; dn^2*0.5 = 0.0625 ; ratio = 256^-0.5 = 0.0625
#define DNORM 0.35355339059327373f
#define HALF_DN2 0.0625f
#define RATIO 0.0625f

typedef _Float16 f16x8 __attribute__((ext_vector_type(8)));
typedef _Float16 f16x2 __attribute__((ext_vector_type(2)));
typedef float f32x4 __attribute__((ext_vector_type(4)));

// XOR-swizzled LDS index for [col][64 l] fp16 tiles: 8-half blocks permuted by col&7
#define SWZ(col, l) ((col) * 64 + (((l) & 7) | ((((((l) >> 3)) ^ (col)) & 7) << 3)))

__device__ __forceinline__ void gload16(const void* g, void* l) {
    __builtin_amdgcn_global_load_lds((const __attribute__((address_space(1))) unsigned*)g,
                                     (__attribute__((address_space(3))) unsigned*)l, 16, 0, 0);
}

// ---------------- fp32 -> fp16 cast (8 elems/thread) ----------------
__global__ __launch_bounds__(256) void cast_f32_f16(const float* __restrict__ in,
                                                    _Float16* __restrict__ out, int n8) {
    int i = blockIdx.x * 256 + threadIdx.x;
    if (i >= n8) return;
    const float4* p = (const float4*)(in + (size_t)i * 8);
    float4 a = p[0], b = p[1];
    f16x8 o;
    o[0] = (_Float16)a.x; o[1] = (_Float16)a.y; o[2] = (_Float16)a.z; o[3] = (_Float16)a.w;
    o[4] = (_Float16)b.x; o[5] = (_Float16)b.y; o[6] = (_Float16)b.z; o[7] = (_Float16)b.w;
    *(f16x8*)(out + (size_t)i * 8) = o;
}

// ---------------- fp16 MFMA GEMM:  C[n][o] = sum_k A[n][k] * W[o][k] ----------------
template <typename CT>
__global__ __launch_bounds__(256) void gemm_f16(const _Float16* __restrict__ A,
                                                const _Float16* __restrict__ W,
                                                CT* __restrict__ C,
                                                int N, int K) {
    __shared__ _Float16 As[128 * 32];
    __shared__ _Float16 Bs[128 * 32];
    const int t    = threadIdx.x;
    const int lane = t & 63;
    const int w    = t >> 6;
    const int wr   = w >> 1, wc = w & 1;
    const int brow = blockIdx.y * 128, bcol = blockIdx.x * 128;

    const int c0 = t, c1 = t + 256;
    const _Float16* Ag0 = A + (size_t)(brow + (c0 >> 2)) * K + (c0 & 3) * 8;
    const _Float16* Ag1 = A + (size_t)(brow + (c1 >> 2)) * K + (c1 & 3) * 8;
    const _Float16* Wg0 = W + (size_t)(bcol + (c0 >> 2)) * K + (c0 & 3) * 8;
    const _Float16* Wg1 = W + (size_t)(bcol + (c1 >> 2)) * K + (c1 & 3) * 8;
    _Float16* Al0 = As + c0 * 8;
    _Float16* Al1 = As + c1 * 8;
    _Float16* Bl0 = Bs + c0 * 8;
    _Float16* Bl1 = Bs + c1 * 8;

    f32x4 acc[4][4];
#pragma unroll
    for (int i = 0; i < 4; i++)
#pragma unroll
        for (int j = 0; j < 4; j++) acc[i][j] = (f32x4){0.f, 0.f, 0.f, 0.f};

    const int fr = lane & 15;
    const int kq = lane >> 4;
    const int aoff = (wr * 64 + fr) * 32 + kq * 8;
    const int boff = (wc * 64 + fr) * 32 + kq * 8;

    for (int k0 = 0; k0 < K; k0 += 32) {
        __syncthreads();
        gload16(Ag0 + k0, Al0);
        gload16(Ag1 + k0, Al1);
        gload16(Wg0 + k0, Bl0);
        gload16(Wg1 + k0, Bl1);
        __syncthreads();
        f16x8 af[4], bf[4];
#pragma unroll
        for (int mi = 0; mi < 4; mi++) af[mi] = *(const f16x8*)&As[aoff + mi * 512];
#pragma unroll
        for (int ni = 0; ni < 4; ni++) bf[ni] = *(const f16x8*)&Bs[boff + ni * 512];
#pragma unroll
        for (int mi = 0; mi < 4; mi++)
#pragma unroll
            for (int ni = 0; ni < 4; ni++)
                acc[mi][ni] = __builtin_amdgcn_mfma_f32_16x16x32_f16(af[mi], bf[ni], acc[mi][ni], 0, 0, 0);
    }
#pragma unroll
    for (int mi = 0; mi < 4; mi++) {
#pragma unroll
        for (int ni = 0; ni < 4; ni++) {
            const int row = brow + wr * 64 + mi * 16 + kq * 4;
            const int col = bcol + wc * 64 + ni * 16 + fr;
#pragma unroll
            for (int r = 0; r < 4; r++)
                C[(size_t)(row + r) * N + col] = (CT)acc[mi][ni][r];
        }
    }
}

// ---------------- MFMA phi_k + kv/ksum partial accumulation ----------------
// grid (NCH, B*H), block 256 (4 waves). Per tile of 64 l-rows:
//   phase1: proj = k @ P^T (k frags direct from global), exp -> phi^T in swizzled LDS
//   phase2: kv[m][d] += phi^T @ v^T (v staged transposed, col 64 = ones -> ksum)
__global__ __launch_bounds__(256) void kv_kernel2(const _Float16* __restrict__ k,
                                                  const _Float16* __restrict__ v,
                                                  const int* __restrict__ mask,
                                                  const _Float16* __restrict__ Ph,
                                                  float* __restrict__ kvpart,
                                                  float* __restrict__ kspart) {
    const int bh = blockIdx.y, b = bh >> 4, h = bh & 15;
    const int ch = blockIdx.x;
    const int t = threadIdx.x, lane = t & 63, w = t >> 6;
    const int fr = lane & 15, kq = lane >> 4;

    __shared__ _Float16 phis[256 * 64];   // [m][l] swizzled
    __shared__ _Float16 vst[80 * 64];     // [d][l] swizzled; row 64 = ones, 65..79 = 0

    // one-time init of vst rows 64..79 (swizzle is a row-internal permutation;
    // rows are constant-valued so linear writes are correct)
    if (t < 128) {
        const int row = 64 + (t >> 3), off = (t & 7) * 8;
        const _Float16 val = (row == 64) ? (_Float16)1.0f : (_Float16)0.0f;
        f16x8 o = {val, val, val, val, val, val, val, val};
        *(f16x8*)&vst[row * 64 + off] = o;
    }

    f32x4 acc[4][5];
#pragma unroll
    for (int mf = 0; mf < 4; mf++)
#pragma unroll
        for (int n2 = 0; n2 < 5; n2++) acc[mf][n2] = (f32x4){0.f, 0.f, 0.f, 0.f};

    const int rr = t & 31, seg = t >> 5;   // v staging: row-pair rr, d-segment seg

    for (int tile = 0; tile < LC / 64; ++tile) {
        const int l0 = ch * LC + tile * 64;

        // ---- stage v transposed (pair-packed b32 writes, conflict-free) ----
        {
            const _Float16* v0 = v + (size_t)(b * L + l0 + 2 * rr) * D + h * DK + seg * 8;
            f16x8 a0 = *(const f16x8*)v0;
            f16x8 a1 = *(const f16x8*)(v0 + D);
#pragma unroll
            for (int j = 0; j < 8; j++) {
                const int d = seg * 8 + j;
                f16x2 pk = {a0[j], a1[j]};
                *(f16x2*)&vst[SWZ(d, 2 * rr)] = pk;
            }
        }

        // ---- phase 1: proj = k @ P^T, k frags direct from global ----
        const _Float16* krow = k + (size_t)(b * L + l0 + w * 16 + fr) * D + h * DK + kq * 8;
        f16x8 ak0 = *(const f16x8*)krow;
        f16x8 ak1 = *(const f16x8*)(krow + 32);
        float ns = 0.f;
#pragma unroll
        for (int j = 0; j < 8; j++)
            ns += (float)ak0[j] * (float)ak0[j] + (float)ak1[j] * (float)ak1[j];
        ns += __shfl_xor(ns, 16);
        ns += __shfl_xor(ns, 32);      // lane now holds full ||k_row||^2 for row w*16+fr
        ns *= HALF_DN2;

        f32x4 pr[16];
#pragma unroll
        for (int nf = 0; nf < 16; nf++) {
            const _Float16* pb = Ph + (nf * 16 + fr) * 64 + kq * 8;
            f16x8 b0 = *(const f16x8*)pb;
            f16x8 b1 = *(const f16x8*)(pb + 32);
            f32x4 c = {0.f, 0.f, 0.f, 0.f};
            c = __builtin_amdgcn_mfma_f32_16x16x32_f16(ak0, b0, c, 0, 0, 0);
            c = __builtin_amdgcn_mfma_f32_16x16x32_f16(ak1, b1, c, 0, 0, 0);
            pr[nf] = c;
        }
        // row max over m (cols): in-lane over nf, then across fr within 16-lane group
        float mx[4] = {-1e30f, -1e30f, -1e30f, -1e30f};
#pragma unroll
        for (int nf = 0; nf < 16; nf++)
#pragma unroll
            for (int r = 0; r < 4; r++) {
                pr[nf][r] *= DNORM;
                mx[r] = fmaxf(mx[r], pr[nf][r]);
            }
#pragma unroll
        for (int r = 0; r < 4; r++) {
            mx[r] = fmaxf(mx[r], __shfl_xor(mx[r], 1));
            mx[r] = fmaxf(mx[r], __shfl_xor(mx[r], 2));
            mx[r] = fmaxf(mx[r], __shfl_xor(mx[r], 4));
            mx[r] = fmaxf(mx[r], __shfl_xor(mx[r], 8));
        }
        float sub[4], mkv[4];
#pragma unroll
        for (int r = 0; r < 4; r++) {
            sub[r] = mx[r] + __shfl(ns, kq * 4 + r);   // ns for row w*16+kq*4+r
            mkv[r] = (float)mask[b * L + l0 + w * 16 + kq * 4 + r];
        }
        // phi -> phi^T LDS (pair-packed b32 writes, 2-way max)
#pragma unroll
        for (int nf = 0; nf < 16; nf++) {
            const int col = nf * 16 + fr;
#pragma unroll
            for (int rp = 0; rp < 2; rp++) {
                const int row = w * 16 + kq * 4 + 2 * rp;
                float v0 = mkv[2 * rp]     * (RATIO * (__expf(pr[nf][2 * rp]     - sub[2 * rp])     + 1e-6f));
                float v1 = mkv[2 * rp + 1] * (RATIO * (__expf(pr[nf][2 * rp + 1] - sub[2 * rp + 1]) + 1e-6f));
                f16x2 pk = {(_Float16)v0, (_Float16)v1};
                *(f16x2*)&phis[SWZ(col, row)] = pk;
            }
        }
        __syncthreads();

        // ---- phase 2: acc[m][d] += phi^T @ v^T ----
        f16x8 bfr[5][2];
#pragma unroll
        for (int n2 = 0; n2 < 5; n2++)
#pragma unroll
            for (int ks = 0; ks < 2; ks++)
                bfr[n2][ks] = *(const f16x8*)&vst[SWZ(n2 * 16 + fr, ks * 32 + kq * 8)];
#pragma unroll
        for (int mf = 0; mf < 4; mf++) {
            const int m = w * 64 + mf * 16 + fr;
            f16x8 a0 = *(const f16x8*)&phis[SWZ(m, kq * 8)];
            f16x8 a1 = *(const f16x8*)&phis[SWZ(m, 32 + kq * 8)];
#pragma unroll
            for (int n2 = 0; n2 < 5; n2++) {
                acc[mf][n2] = __builtin_amdgcn_mfma_f32_16x16x32_f16(a0, bfr[n2][0], acc[mf][n2], 0, 0, 0);
                acc[mf][n2] = __builtin_amdgcn_mfma_f32_16x16x32_f16(a1, bfr[n2][1], acc[mf][n2], 0, 0, 0);
            }
        }
        __syncthreads();
    }

    // ---- write partials: m = w*64 + mf*16 + kq*4 + r, d = n2*16 + fr ----
    float* kvp = kvpart + ((size_t)ch * 64 + bh) * M * DK;
    float* ksp = kspart + ((size_t)ch * 64 + bh) * M;
#pragma unroll
    for (int mf = 0; mf < 4; mf++) {
#pragma unroll
        for (int r = 0; r < 4; r++) {
            const int m = w * 64 + mf * 16 + kq * 4 + r;
#pragma unroll
            for (int n2 = 0; n2 < 4; n2++)
                kvp[(size_t)m * DK + n2 * 16 + fr] = acc[mf][n2][r];
            if (fr == 0) ksp[m] = acc[mf][4][r];
        }
    }
}

// ---------------- reduce partials -> kvt fp16 [bh][80][256] (col 64 = ksum, 65..79 = 0) ----------------
__global__ __launch_bounds__(256) void reduce_kvt(const float* __restrict__ kvp,
                                                  const float* __restrict__ ksp,
                                                  _Float16* __restrict__ kvt) {
    const int bh = blockIdx.x;
    const int t  = threadIdx.x;   // m index
    float s[64];
#pragma unroll
    for (int c = 0; c < 64; c++) s[c] = 0.f;
    float s64 = 0.f;
    for (int ch = 0; ch < NCH; ch++) {
        const float* src = kvp + (((size_t)ch * 64 + bh) * M + t) * DK;
#pragma unroll
        for (int c4 = 0; c4 < 16; c4++) {
            float4 v = *(const float4*)(src + c4 * 4);
            s[c4 * 4 + 0] += v.x; s[c4 * 4 + 1] += v.y;
            s[c4 * 4 + 2] += v.z; s[c4 * 4 + 3] += v.w;
        }
        s64 += ksp[((size_t)ch * 64 + bh) * M + t];
    }
    _Float16* dst = kvt + (size_t)bh * 80 * 256;
#pragma unroll
    for (int c = 0; c < 64; c++) dst[c * 256 + t] = (_Float16)s[c];
    dst[64 * 256 + t] = (_Float16)s64;
#pragma unroll
    for (int c = 65; c < 80; c++) dst[c * 256 + t] = (_Float16)0.f;
}

// ---------------- fused phi_q + out + denom + normalize, MFMA ----------------
__global__ __launch_bounds__(256) void out_kernel2(const _Float16* __restrict__ q,
                                                   const _Float16* __restrict__ Ph,
                                                   const _Float16* __restrict__ kvt,
                                                   _Float16* __restrict__ ao) {
    const int bh = blockIdx.y, b = bh >> 4, h = bh & 15;
    const int l0 = blockIdx.x * 64;
    const int t = threadIdx.x, lane = t & 63, w = t >> 6;
    const int fr = lane & 15, kq = lane >> 4;

    __shared__ _Float16 qs[64 * 72];
    __shared__ _Float16 phis[64 * 264];
    __shared__ float rnsq[64];

    {
        const int row = t >> 2, seg = t & 3;
        const _Float16* src = q + (size_t)(b * L + l0 + row) * D + h * DK + seg * 16;
        f16x8 a0 = *(const f16x8*)src;
        f16x8 a1 = *(const f16x8*)(src + 8);
        *(f16x8*)&qs[row * 72 + seg * 16] = a0;
        *(f16x8*)&qs[row * 72 + seg * 16 + 8] = a1;
        float ns = 0.f;
#pragma unroll
        for (int j = 0; j < 8; j++)
            ns += (float)a0[j] * (float)a0[j] + (float)a1[j] * (float)a1[j];
        ns += __shfl_xor(ns, 1);
        ns += __shfl_xor(ns, 2);
        if (seg == 0) rnsq[row] = ns * HALF_DN2;
    }
    __syncthreads();

    f16x8 aq0 = *(const f16x8*)&qs[(w * 16 + fr) * 72 + kq * 8];
    f16x8 aq1 = *(const f16x8*)&qs[(w * 16 + fr) * 72 + kq * 8 + 32];
    f32x4 pr[16];
#pragma unroll
    for (int nf = 0; nf < 16; nf++) {
        const _Float16* pb = Ph + (nf * 16 + fr) * 64 + kq * 8;
        f16x8 b0 = *(const f16x8*)pb;
        f16x8 b1 = *(const f16x8*)(pb + 32);
        f32x4 c = {0.f, 0.f, 0.f, 0.f};
        c = __builtin_amdgcn_mfma_f32_16x16x32_f16(aq0, b0, c, 0, 0, 0);
        c = __builtin_amdgcn_mfma_f32_16x16x32_f16(aq1, b1, c, 0, 0, 0);
        pr[nf] = c;
    }
    float mx[4] = {-1e30f, -1e30f, -1e30f, -1e30f};
#pragma unroll
    for (int nf = 0; nf < 16; nf++)
#pragma unroll
        for (int r = 0; r < 4; r++) {
            pr[nf][r] *= DNORM;
            mx[r] = fmaxf(mx[r], pr[nf][r]);
        }
#pragma unroll
    for (int r = 0; r < 4; r++) {
        mx[r] = fmaxf(mx[r], __shfl_xor(mx[r], 1));
        mx[r] = fmaxf(mx[r], __shfl_xor(mx[r], 2));
        mx[r] = fmaxf(mx[r], __shfl_xor(mx[r], 4));
        mx[r] = fmaxf(mx[r], __shfl_xor(mx[r], 8));
    }
    float sub[4];
#pragma unroll
    for (int r = 0; r < 4; r++) sub[r] = mx[r] + rnsq[w * 16 + kq * 4 + r];
#pragma unroll
    for (int nf = 0; nf < 16; nf++)
#pragma unroll
        for (int r = 0; r < 4; r++) {
            float val = RATIO * (__expf(pr[nf][r] - sub[r]) + 1e-6f);
            phis[(w * 16 + kq * 4 + r) * 264 + nf * 16 + fr] = (_Float16)val;
        }
    __syncthreads();

    f32x4 acc[5];
#pragma unroll
    for (int n2 = 0; n2 < 5; n2++) acc[n2] = (f32x4){0.f, 0.f, 0.f, 0.f};
    const _Float16* kvb = kvt + (size_t)bh * 80 * 256;
#pragma unroll
    for (int ks = 0; ks < 8; ks++) {
        f16x8 af = *(const f16x8*)&phis[(w * 16 + fr) * 264 + kq * 8 + ks * 32];
#pragma unroll
        for (int n2 = 0; n2 < 5; n2++) {
            f16x8 bf = *(const f16x8*)&kvb[(n2 * 16 + fr) * 256 + kq * 8 + ks * 32];
            acc[n2] = __builtin_amdgcn_mfma_f32_16x16x32_f16(af, bf, acc[n2], 0, 0, 0);
        }
    }
#pragma unroll
    for (int r = 0; r < 4; r++) {
        float den = __shfl(acc[4][r], (lane & 48));
        float inv = 1.f / fmaxf(den, 1e-6f);
        const int row = l0 + w * 16 + kq * 4 + r;
        _Float16* dst = ao + (size_t)(b * L + row) * D + h * DK;
#pragma unroll
        for (int n2 = 0; n2 < 4; n2++)
            dst[n2 * 16 + fr] = (_Float16)(acc[n2][r] * inv);
    }
}

extern "C" void kernel_launch(void* const* d_in, const int* in_sizes, int n_in,
                              void* d_out, int out_size, void* d_ws, size_t ws_size,
                              hipStream_t stream) {
    (void)in_sizes; (void)n_in; (void)out_size; (void)ws_size;
    const float* X    = (const float*)d_in[0];
    const int*   mask = (const int*)d_in[1];
    const float* Wq   = (const float*)d_in[2];
    const float* Wk   = (const float*)d_in[3];
    const float* Wv   = (const float*)d_in[4];
    const float* Wo   = (const float*)d_in[5];
    const float* P    = (const float*)d_in[6];

    char* ws = (char*)d_ws;
    _Float16* bufK  = (_Float16*)ws;                      // k, later attn (32MB)
    _Float16* bufVQ = (_Float16*)(ws + 33554432);         // v, later q    (32MB)
    float* kvpart   = (float*)(ws + 67108864);            // 32MB
    float* kspart   = (float*)(ws + 100663296);           // 512KB
    _Float16* kvt   = (_Float16*)(ws + 101187584);        // 2.62MB
    _Float16* Xh    = (_Float16*)(ws + 103809024);        // 32MB
    _Float16* Wkh   = (_Float16*)(ws + 137363456);        // 2MB
    _Float16* Wvh   = (_Float16*)(ws + 139460608);        // 2MB
    _Float16* Wqh   = (_Float16*)(ws + 141557760);        // 2MB
    _Float16* Woh   = (_Float16*)(ws + 143654912);        // 2MB
    _Float16* Ph    = (_Float16*)(ws + 145752064);        // 32KB -> ~145.8MB total
    float* out      = (float*)d_out;

    dim3 blk(256);
    hipLaunchKernelGGL(cast_f32_f16, dim3(8192), blk, 0, stream, X, Xh, 2097152);
    hipLaunchKernelGGL(cast_f32_f16, dim3(512), blk, 0, stream, Wk, Wkh, 131072);
    hipLaunchKernelGGL(cast_f32_f16, dim3(512), blk, 0, stream, Wv, Wvh, 131072);
    hipLaunchKernelGGL(cast_f32_f16, dim3(512), blk, 0, stream, Wq, Wqh, 131072);
    hipLaunchKernelGGL(cast_f32_f16, dim3(512), blk, 0, stream, Wo, Woh, 131072);
    hipLaunchKernelGGL(cast_f32_f16, dim3(8), blk, 0, stream, P, Ph, 2048);

    dim3 gg(8, 128);
    hipLaunchKernelGGL((gemm_f16<_Float16>), gg, blk, 0, stream, Xh, Wkh, bufK, D, D);
    hipLaunchKernelGGL((gemm_f16<_Float16>), gg, blk, 0, stream, Xh, Wvh, bufVQ, D, D);
    hipLaunchKernelGGL(kv_kernel2, dim3(NCH, B * H), blk, 0, stream, bufK, bufVQ, mask, Ph, kvpart, kspart);
    hipLaunchKernelGGL(reduce_kvt, dim3(64), blk, 0, stream, kvpart, kspart, kvt);
    hipLaunchKernelGGL((gemm_f16<_Float16>), gg, blk, 0, stream, Xh, Wqh, bufVQ, D, D);
    hipLaunchKernelGGL(out_kernel2, dim3(L / 64, B * H), blk, 0, stream, bufVQ, Ph, kvt, bufK);
    hipLaunchKernelGGL((gemm_f16<float>), gg, blk, 0, stream, bufK, Woh, out, D, D);
}

// Round 5
// 434.544 us; speedup vs baseline: 9.0668x; 1.1407x over previous
//
#include <hip/hip_runtime.h>
#include <math.h>

#define B 4
#define L 4096
#define D 1024
#define H 16
#define DK 64
#define M 256
#define NTOK (B*L)        // 16384
#define NCH 8
#define LC (L/NCH)        // 512

// dn = 64^-0.25 = 2^-1.5 ; dn^2*0.5 = 0.0625 ; ratio = 256^-0.5 = 0.0625
#define DNORM 0.35355339059327373f
#define HALF_DN2 0.0625f
#define RATIO 0.0625f

typedef _Float16 f16x8 __attribute__((ext_vector_type(8)));
typedef _Float16 f16x2 __attribute__((ext_vector_type(2)));
typedef float f32x4 __attribute__((ext_vector_type(4)));

// XOR-swizzled LDS index for [col][64 l] fp16 tiles: 8-half blocks permuted by col&7
#define SWZ(col, l) ((col) * 64 + (((l) & 7) | ((((((l) >> 3)) ^ (col)) & 7) << 3)))

__device__ __forceinline__ void gload16(const void* g, void* l) {
    __builtin_amdgcn_global_load_lds((const __attribute__((address_space(1))) unsigned*)g,
                                     (__attribute__((address_space(3))) unsigned*)l, 16, 0, 0);
}

// ---------------- fp32 -> fp16 cast (8 elems/thread) ----------------
__global__ __launch_bounds__(256) void cast_f32_f16(const float* __restrict__ in,
                                                    _Float16* __restrict__ out, int n8) {
    int i = blockIdx.x * 256 + threadIdx.x;
    if (i >= n8) return;
    const float4* p = (const float4*)(in + (size_t)i * 8);
    float4 a = p[0], b = p[1];
    f16x8 o;
    o[0] = (_Float16)a.x; o[1] = (_Float16)a.y; o[2] = (_Float16)a.z; o[3] = (_Float16)a.w;
    o[4] = (_Float16)b.x; o[5] = (_Float16)b.y; o[6] = (_Float16)b.z; o[7] = (_Float16)b.w;
    *(f16x8*)(out + (size_t)i * 8) = o;
}

// ---------------- fp16 MFMA GEMM:  C[n][o] = sum_k A[n][k] * W[o][k] ----------------
template <typename CT>
__global__ __launch_bounds__(256) void gemm_f16(const _Float16* __restrict__ A,
                                                const _Float16* __restrict__ W,
                                                CT* __restrict__ C,
                                                int N, int K) {
    __shared__ _Float16 As[128 * 32];
    __shared__ _Float16 Bs[128 * 32];
    const int t    = threadIdx.x;
    const int lane = t & 63;
    const int w    = t >> 6;
    const int wr   = w >> 1, wc = w & 1;
    const int brow = blockIdx.y * 128, bcol = blockIdx.x * 128;

    const int c0 = t, c1 = t + 256;
    const _Float16* Ag0 = A + (size_t)(brow + (c0 >> 2)) * K + (c0 & 3) * 8;
    const _Float16* Ag1 = A + (size_t)(brow + (c1 >> 2)) * K + (c1 & 3) * 8;
    const _Float16* Wg0 = W + (size_t)(bcol + (c0 >> 2)) * K + (c0 & 3) * 8;
    const _Float16* Wg1 = W + (size_t)(bcol + (c1 >> 2)) * K + (c1 & 3) * 8;
    _Float16* Al0 = As + c0 * 8;
    _Float16* Al1 = As + c1 * 8;
    _Float16* Bl0 = Bs + c0 * 8;
    _Float16* Bl1 = Bs + c1 * 8;

    f32x4 acc[4][4];
#pragma unroll
    for (int i = 0; i < 4; i++)
#pragma unroll
        for (int j = 0; j < 4; j++) acc[i][j] = (f32x4){0.f, 0.f, 0.f, 0.f};

    const int fr = lane & 15;
    const int kq = lane >> 4;
    const int aoff = (wr * 64 + fr) * 32 + kq * 8;
    const int boff = (wc * 64 + fr) * 32 + kq * 8;

    for (int k0 = 0; k0 < K; k0 += 32) {
        __syncthreads();
        gload16(Ag0 + k0, Al0);
        gload16(Ag1 + k0, Al1);
        gload16(Wg0 + k0, Bl0);
        gload16(Wg1 + k0, Bl1);
        __syncthreads();
        f16x8 af[4], bf[4];
#pragma unroll
        for (int mi = 0; mi < 4; mi++) af[mi] = *(const f16x8*)&As[aoff + mi * 512];
#pragma unroll
        for (int ni = 0; ni < 4; ni++) bf[ni] = *(const f16x8*)&Bs[boff + ni * 512];
#pragma unroll
        for (int mi = 0; mi < 4; mi++)
#pragma unroll
            for (int ni = 0; ni < 4; ni++)
                acc[mi][ni] = __builtin_amdgcn_mfma_f32_16x16x32_f16(af[mi], bf[ni], acc[mi][ni], 0, 0, 0);
    }
#pragma unroll
    for (int mi = 0; mi < 4; mi++) {
#pragma unroll
        for (int ni = 0; ni < 4; ni++) {
            const int row = brow + wr * 64 + mi * 16 + kq * 4;
            const int col = bcol + wc * 64 + ni * 16 + fr;
#pragma unroll
            for (int r = 0; r < 4; r++)
                C[(size_t)(row + r) * N + col] = (CT)acc[mi][ni][r];
        }
    }
}

// ---------------- MFMA phi_k + kv/ksum partial accumulation ----------------
__global__ __launch_bounds__(256) void kv_kernel2(const _Float16* __restrict__ k,
                                                  const _Float16* __restrict__ v,
                                                  const int* __restrict__ mask,
                                                  const _Float16* __restrict__ Ph,
                                                  float* __restrict__ kvpart,
                                                  float* __restrict__ kspart) {
    const int bh = blockIdx.y, b = bh >> 4, h = bh & 15;
    const int ch = blockIdx.x;
    const int t = threadIdx.x, lane = t & 63, w = t >> 6;
    const int fr = lane & 15, kq = lane >> 4;

    __shared__ _Float16 phis[256 * 64];   // [m][l] swizzled
    __shared__ _Float16 vst[80 * 64];     // [d][l] swizzled; row 64 = ones, 65..79 = 0

    if (t < 128) {
        const int row = 64 + (t >> 3), off = (t & 7) * 8;
        const _Float16 val = (row == 64) ? (_Float16)1.0f : (_Float16)0.0f;
        f16x8 o = {val, val, val, val, val, val, val, val};
        *(f16x8*)&vst[row * 64 + off] = o;
    }

    f32x4 acc[4][5];
#pragma unroll
    for (int mf = 0; mf < 4; mf++)
#pragma unroll
        for (int n2 = 0; n2 < 5; n2++) acc[mf][n2] = (f32x4){0.f, 0.f, 0.f, 0.f};

    const int rr = t & 31, seg = t >> 5;

    for (int tile = 0; tile < LC / 64; ++tile) {
        const int l0 = ch * LC + tile * 64;

        {
            const _Float16* v0 = v + (size_t)(b * L + l0 + 2 * rr) * D + h * DK + seg * 8;
            f16x8 a0 = *(const f16x8*)v0;
            f16x8 a1 = *(const f16x8*)(v0 + D);
#pragma unroll
            for (int j = 0; j < 8; j++) {
                const int d = seg * 8 + j;
                f16x2 pk = {a0[j], a1[j]};
                *(f16x2*)&vst[SWZ(d, 2 * rr)] = pk;
            }
        }

        const _Float16* krow = k + (size_t)(b * L + l0 + w * 16 + fr) * D + h * DK + kq * 8;
        f16x8 ak0 = *(const f16x8*)krow;
        f16x8 ak1 = *(const f16x8*)(krow + 32);
        float ns = 0.f;
#pragma unroll
        for (int j = 0; j < 8; j++)
            ns += (float)ak0[j] * (float)ak0[j] + (float)ak1[j] * (float)ak1[j];
        ns += __shfl_xor(ns, 16);
        ns += __shfl_xor(ns, 32);
        ns *= HALF_DN2;

        f32x4 pr[16];
#pragma unroll
        for (int nf = 0; nf < 16; nf++) {
            const _Float16* pb = Ph + (nf * 16 + fr) * 64 + kq * 8;
            f16x8 b0 = *(const f16x8*)pb;
            f16x8 b1 = *(const f16x8*)(pb + 32);
            f32x4 c = {0.f, 0.f, 0.f, 0.f};
            c = __builtin_amdgcn_mfma_f32_16x16x32_f16(ak0, b0, c, 0, 0, 0);
            c = __builtin_amdgcn_mfma_f32_16x16x32_f16(ak1, b1, c, 0, 0, 0);
            pr[nf] = c;
        }
        float mx[4] = {-1e30f, -1e30f, -1e30f, -1e30f};
#pragma unroll
        for (int nf = 0; nf < 16; nf++)
#pragma unroll
            for (int r = 0; r < 4; r++) {
                pr[nf][r] *= DNORM;
                mx[r] = fmaxf(mx[r], pr[nf][r]);
            }
#pragma unroll
        for (int r = 0; r < 4; r++) {
            mx[r] = fmaxf(mx[r], __shfl_xor(mx[r], 1));
            mx[r] = fmaxf(mx[r], __shfl_xor(mx[r], 2));
            mx[r] = fmaxf(mx[r], __shfl_xor(mx[r], 4));
            mx[r] = fmaxf(mx[r], __shfl_xor(mx[r], 8));
        }
        float sub[4], mkv[4];
#pragma unroll
        for (int r = 0; r < 4; r++) {
            sub[r] = mx[r] + __shfl(ns, kq * 4 + r);
            mkv[r] = (float)mask[b * L + l0 + w * 16 + kq * 4 + r];
        }
#pragma unroll
        for (int nf = 0; nf < 16; nf++) {
            const int col = nf * 16 + fr;
#pragma unroll
            for (int rp = 0; rp < 2; rp++) {
                const int row = w * 16 + kq * 4 + 2 * rp;
                float v0 = mkv[2 * rp]     * (RATIO * (__expf(pr[nf][2 * rp]     - sub[2 * rp])     + 1e-6f));
                float v1 = mkv[2 * rp + 1] * (RATIO * (__expf(pr[nf][2 * rp + 1] - sub[2 * rp + 1]) + 1e-6f));
                f16x2 pk = {(_Float16)v0, (_Float16)v1};
                *(f16x2*)&phis[SWZ(col, row)] = pk;
            }
        }
        __syncthreads();

        f16x8 bfr[5][2];
#pragma unroll
        for (int n2 = 0; n2 < 5; n2++)
#pragma unroll
            for (int ks = 0; ks < 2; ks++)
                bfr[n2][ks] = *(const f16x8*)&vst[SWZ(n2 * 16 + fr, ks * 32 + kq * 8)];
#pragma unroll
        for (int mf = 0; mf < 4; mf++) {
            const int m = w * 64 + mf * 16 + fr;
            f16x8 a0 = *(const f16x8*)&phis[SWZ(m, kq * 8)];
            f16x8 a1 = *(const f16x8*)&phis[SWZ(m, 32 + kq * 8)];
#pragma unroll
            for (int n2 = 0; n2 < 5; n2++) {
                acc[mf][n2] = __builtin_amdgcn_mfma_f32_16x16x32_f16(a0, bfr[n2][0], acc[mf][n2], 0, 0, 0);
                acc[mf][n2] = __builtin_amdgcn_mfma_f32_16x16x32_f16(a1, bfr[n2][1], acc[mf][n2], 0, 0, 0);
            }
        }
        __syncthreads();
    }

    float* kvp = kvpart + ((size_t)ch * 64 + bh) * M * DK;
    float* ksp = kspart + ((size_t)ch * 64 + bh) * M;
#pragma unroll
    for (int mf = 0; mf < 4; mf++) {
#pragma unroll
        for (int r = 0; r < 4; r++) {
            const int m = w * 64 + mf * 16 + kq * 4 + r;
#pragma unroll
            for (int n2 = 0; n2 < 4; n2++)
                kvp[(size_t)m * DK + n2 * 16 + fr] = acc[mf][n2][r];
            if (fr == 0) ksp[m] = acc[mf][4][r];
        }
    }
}

// ---------------- reduce partials -> kvt fp16 [bh][80][256], PRE-SWIZZLED ----------------
// data chunk c (16B) of row r stored at chunk position c^(r&7); col 64-group = ksum.
__global__ __launch_bounds__(256) void reduce_kvt(const float* __restrict__ kvp,
                                                  const float* __restrict__ ksp,
                                                  _Float16* __restrict__ kvt) {
    const int bh = blockIdx.x;
    const int t  = threadIdx.x;   // m index (column)
    float s[64];
#pragma unroll
    for (int c = 0; c < 64; c++) s[c] = 0.f;
    float s64 = 0.f;
    for (int ch = 0; ch < NCH; ch++) {
        const float* src = kvp + (((size_t)ch * 64 + bh) * M + t) * DK;
#pragma unroll
        for (int c4 = 0; c4 < 16; c4++) {
            float4 v = *(const float4*)(src + c4 * 4);
            s[c4 * 4 + 0] += v.x; s[c4 * 4 + 1] += v.y;
            s[c4 * 4 + 2] += v.z; s[c4 * 4 + 3] += v.w;
        }
        s64 += ksp[((size_t)ch * 64 + bh) * M + t];
    }
    _Float16* dst = kvt + (size_t)bh * 80 * 256;
    const int chunk = t >> 3, within = t & 7;
#pragma unroll
    for (int r = 0; r < 64; r++)
        dst[r * 256 + ((chunk ^ (r & 7)) << 3) + within] = (_Float16)s[r];
    dst[64 * 256 + t] = (_Float16)s64;      // row 64: 64&7==0 -> linear
#pragma unroll
    for (int r = 65; r < 80; r++)
        dst[r * 256 + t] = (_Float16)0.f;   // zeros: swizzle-invariant
}

// ---------------- fused phi_q + out + denom + normalize, MFMA, LDS-staged kvt ----------------
// grid (L/64, B*H), block 256 (4 waves).
__global__ __launch_bounds__(256) void out_kernel3(const _Float16* __restrict__ q,
                                                   const _Float16* __restrict__ Ph,
                                                   const _Float16* __restrict__ kvtg,
                                                   _Float16* __restrict__ ao) {
    const int bh = blockIdx.y, b = bh >> 4, h = bh & 15;
    const int l0 = blockIdx.x * 64;
    const int t = threadIdx.x, lane = t & 63, w = t >> 6;
    const int fr = lane & 15, kq = lane >> 4;

    __shared__ _Float16 phis[64 * 256];   // [l][m], chunk^=(l&7) swizzle
    __shared__ _Float16 kvs[80 * 256];    // swizzled image of kvtg[bh]

    // ---- issue kvt staging first (hidden under phase 1) ----
    {
        const _Float16* src = kvtg + (size_t)bh * 80 * 256 + t * 8;
        _Float16* dst = kvs + t * 8;
#pragma unroll
        for (int i = 0; i < 10; i++)
            gload16(src + i * 2048, dst + i * 2048);
    }

    // ---- q fragments direct from global + row norm ----
    const _Float16* qp = q + (size_t)(b * L + l0 + w * 16 + fr) * D + h * DK + kq * 8;
    f16x8 aq0 = *(const f16x8*)qp;
    f16x8 aq1 = *(const f16x8*)(qp + 32);
    float ns = 0.f;
#pragma unroll
    for (int j = 0; j < 8; j++)
        ns += (float)aq0[j] * (float)aq0[j] + (float)aq1[j] * (float)aq1[j];
    ns += __shfl_xor(ns, 16);
    ns += __shfl_xor(ns, 32);
    ns *= HALF_DN2;

    // ---- phase 1: proj = q @ P^T ----
    f32x4 pr[16];
#pragma unroll
    for (int nf = 0; nf < 16; nf++) {
        const _Float16* pb = Ph + (nf * 16 + fr) * 64 + kq * 8;
        f16x8 b0 = *(const f16x8*)pb;
        f16x8 b1 = *(const f16x8*)(pb + 32);
        f32x4 c = {0.f, 0.f, 0.f, 0.f};
        c = __builtin_amdgcn_mfma_f32_16x16x32_f16(aq0, b0, c, 0, 0, 0);
        c = __builtin_amdgcn_mfma_f32_16x16x32_f16(aq1, b1, c, 0, 0, 0);
        pr[nf] = c;
    }
    float mx[4] = {-1e30f, -1e30f, -1e30f, -1e30f};
#pragma unroll
    for (int nf = 0; nf < 16; nf++)
#pragma unroll
        for (int r = 0; r < 4; r++) {
            pr[nf][r] *= DNORM;
            mx[r] = fmaxf(mx[r], pr[nf][r]);
        }
#pragma unroll
    for (int r = 0; r < 4; r++) {
        mx[r] = fmaxf(mx[r], __shfl_xor(mx[r], 1));
        mx[r] = fmaxf(mx[r], __shfl_xor(mx[r], 2));
        mx[r] = fmaxf(mx[r], __shfl_xor(mx[r], 4));
        mx[r] = fmaxf(mx[r], __shfl_xor(mx[r], 8));
    }
    float sub[4];
#pragma unroll
    for (int r = 0; r < 4; r++) sub[r] = mx[r] + __shfl(ns, kq * 4 + r);
    // phi -> swizzled LDS: position row*256 + ((colchunk ^ (row&7))<<3) + (col&7)
#pragma unroll
    for (int nf = 0; nf < 16; nf++) {
        const int cch = nf * 2 + (fr >> 3), cw = fr & 7;
#pragma unroll
        for (int r = 0; r < 4; r++) {
            const int row = w * 16 + kq * 4 + r;
            float val = RATIO * (__expf(pr[nf][r] - sub[r]) + 1e-6f);
            phis[row * 256 + ((cch ^ (row & 7)) << 3) + cw] = (_Float16)val;
        }
    }
    __syncthreads();   // drains lgkm + vmcnt: phis ready AND kvs staged

    // ---- phase 2: out[64][80] = phi @ kvs^T (row 64 = denom) ----
    f32x4 acc[5];
#pragma unroll
    for (int n2 = 0; n2 < 5; n2++) acc[n2] = (f32x4){0.f, 0.f, 0.f, 0.f};
    const int arow = w * 16 + fr;
#pragma unroll
    for (int ks = 0; ks < 8; ks++) {
        const int c = ks * 4 + kq;
        f16x8 af = *(const f16x8*)&phis[arow * 256 + ((c ^ (arow & 7)) << 3)];
#pragma unroll
        for (int n2 = 0; n2 < 5; n2++) {
            const int n = n2 * 16 + fr;
            f16x8 bf = *(const f16x8*)&kvs[n * 256 + ((c ^ (n & 7)) << 3)];
            acc[n2] = __builtin_amdgcn_mfma_f32_16x16x32_f16(af, bf, acc[n2], 0, 0, 0);
        }
    }
    // ---- normalize + write ----
#pragma unroll
    for (int r = 0; r < 4; r++) {
        float den = __shfl(acc[4][r], (lane & 48));   // fr==0 lane holds ksum col
        float inv = 1.f / fmaxf(den, 1e-6f);
        const int row = l0 + w * 16 + kq * 4 + r;
        _Float16* dst = ao + (size_t)(b * L + row) * D + h * DK;
#pragma unroll
        for (int n2 = 0; n2 < 4; n2++)
            dst[n2 * 16 + fr] = (_Float16)(acc[n2][r] * inv);
    }
}

extern "C" void kernel_launch(void* const* d_in, const int* in_sizes, int n_in,
                              void* d_out, int out_size, void* d_ws, size_t ws_size,
                              hipStream_t stream) {
    (void)in_sizes; (void)n_in; (void)out_size; (void)ws_size;
    const float* X    = (const float*)d_in[0];
    const int*   mask = (const int*)d_in[1];
    const float* Wq   = (const float*)d_in[2];
    const float* Wk   = (const float*)d_in[3];
    const float* Wv   = (const float*)d_in[4];
    const float* Wo   = (const float*)d_in[5];
    const float* P    = (const float*)d_in[6];

    char* ws = (char*)d_ws;
    _Float16* bufK  = (_Float16*)ws;                      // k, later attn (32MB)
    _Float16* bufVQ = (_Float16*)(ws + 33554432);         // v, later q    (32MB)
    float* kvpart   = (float*)(ws + 67108864);            // 32MB
    float* kspart   = (float*)(ws + 100663296);           // 512KB
    _Float16* kvt   = (_Float16*)(ws + 101187584);        // 2.62MB
    _Float16* Xh    = (_Float16*)(ws + 103809024);        // 32MB
    _Float16* Wkh   = (_Float16*)(ws + 137363456);        // 2MB
    _Float16* Wvh   = (_Float16*)(ws + 139460608);        // 2MB
    _Float16* Wqh   = (_Float16*)(ws + 141557760);        // 2MB
    _Float16* Woh   = (_Float16*)(ws + 143654912);        // 2MB
    _Float16* Ph    = (_Float16*)(ws + 145752064);        // 32KB -> ~145.8MB total
    float* out      = (float*)d_out;

    dim3 blk(256);
    hipLaunchKernelGGL(cast_f32_f16, dim3(8192), blk, 0, stream, X, Xh, 2097152);
    hipLaunchKernelGGL(cast_f32_f16, dim3(512), blk, 0, stream, Wk, Wkh, 131072);
    hipLaunchKernelGGL(cast_f32_f16, dim3(512), blk, 0, stream, Wv, Wvh, 131072);
    hipLaunchKernelGGL(cast_f32_f16, dim3(512), blk, 0, stream, Wq, Wqh, 131072);
    hipLaunchKernelGGL(cast_f32_f16, dim3(512), blk, 0, stream, Wo, Woh, 131072);
    hipLaunchKernelGGL(cast_f32_f16, dim3(8), blk, 0, stream, P, Ph, 2048);

    dim3 gg(8, 128);
    hipLaunchKernelGGL((gemm_f16<_Float16>), gg, blk, 0, stream, Xh, Wkh, bufK, D, D);
    hipLaunchKernelGGL((gemm_f16<_Float16>), gg, blk, 0, stream, Xh, Wvh, bufVQ, D, D);
    hipLaunchKernelGGL(kv_kernel2, dim3(NCH, B * H), blk, 0, stream, bufK, bufVQ, mask, Ph, kvpart, kspart);
    hipLaunchKernelGGL(reduce_kvt, dim3(64), blk, 0, stream, kvpart, kspart, kvt);
    hipLaunchKernelGGL((gemm_f16<_Float16>), gg, blk, 0, stream, Xh, Wqh, bufVQ, D, D);
    hipLaunchKernelGGL(out_kernel3, dim3(L / 64, B * H), blk, 0, stream, bufVQ, Ph, kvt, bufK);
    hipLaunchKernelGGL((gemm_f16<float>), gg, blk, 0, stream, bufK, Woh, out, D, D);
}

// Round 6
// 425.904 us; speedup vs baseline: 9.2508x; 1.0203x over previous
//
#include <hip/hip_runtime.h>
#include <math.h>

#define B 4
#define L 4096
#define D 1024
#define H 16
#define DK 64
#define M 256
#define NTOK (B*L)        // 16384
#define NCH 8
#define LC (L/NCH)        // 512

// dn = 64^-0.25 = 2^-1.5 ; dn^2*0.5 = 0.0625 ; ratio = 256^-0.5 = 0.0625
#define DNORM 0.35355339059327373f
#define HALF_DN2 0.0625f
#define RATIO 0.0625f

typedef _Float16 f16x8 __attribute__((ext_vector_type(8)));
typedef _Float16 f16x2 __attribute__((ext_vector_type(2)));
typedef float f32x4 __attribute__((ext_vector_type(4)));

// XOR-swizzled LDS index for [col][64 l] fp16 tiles: 8-half blocks permuted by col&7
#define SWZ(col, l) ((col) * 64 + (((l) & 7) | ((((((l) >> 3)) ^ (col)) & 7) << 3)))

__device__ __forceinline__ void gload16(const void* g, void* l) {
    __builtin_amdgcn_global_load_lds((const __attribute__((address_space(1))) unsigned*)g,
                                     (__attribute__((address_space(3))) unsigned*)l, 16, 0, 0);
}

// ---------------- fp32 -> fp16 cast (8 elems/thread) ----------------
__global__ __launch_bounds__(256) void cast_f32_f16(const float* __restrict__ in,
                                                    _Float16* __restrict__ out, int n8) {
    int i = blockIdx.x * 256 + threadIdx.x;
    if (i >= n8) return;
    const float4* p = (const float4*)(in + (size_t)i * 8);
    float4 a = p[0], b = p[1];
    f16x8 o;
    o[0] = (_Float16)a.x; o[1] = (_Float16)a.y; o[2] = (_Float16)a.z; o[3] = (_Float16)a.w;
    o[4] = (_Float16)b.x; o[5] = (_Float16)b.y; o[6] = (_Float16)b.z; o[7] = (_Float16)b.w;
    *(f16x8*)(out + (size_t)i * 8) = o;
}

// ---------------- P fp32 [256][64] -> fp16 pre-swizzled global image ----------------
// output chunk c = row*8 + p (16B) contains row's source chunk (p ^ (row&7)).
__global__ __launch_bounds__(256) void cast_P_swz(const float* __restrict__ P,
                                                  _Float16* __restrict__ Phs) {
    const int t = threadIdx.x;
#pragma unroll
    for (int i = 0; i < 8; i++) {
        const int c = t + i * 256;
        const int row = c >> 3, p = c & 7;
        const int sc = p ^ (row & 7);
        const float* src = P + row * 64 + sc * 8;
        f16x8 o;
#pragma unroll
        for (int j = 0; j < 8; j++) o[j] = (_Float16)src[j];
        *(f16x8*)(Phs + (size_t)c * 8) = o;
    }
}

// ---------------- fp16 MFMA GEMM:  C[n][o] = sum_k A[n][k] * W[o][k] ----------------
template <typename CT>
__global__ __launch_bounds__(256) void gemm_f16(const _Float16* __restrict__ A,
                                                const _Float16* __restrict__ W,
                                                CT* __restrict__ C,
                                                int N, int K) {
    __shared__ _Float16 As[128 * 32];
    __shared__ _Float16 Bs[128 * 32];
    const int t    = threadIdx.x;
    const int lane = t & 63;
    const int w    = t >> 6;
    const int wr   = w >> 1, wc = w & 1;
    const int brow = blockIdx.y * 128, bcol = blockIdx.x * 128;

    const int c0 = t, c1 = t + 256;
    const _Float16* Ag0 = A + (size_t)(brow + (c0 >> 2)) * K + (c0 & 3) * 8;
    const _Float16* Ag1 = A + (size_t)(brow + (c1 >> 2)) * K + (c1 & 3) * 8;
    const _Float16* Wg0 = W + (size_t)(bcol + (c0 >> 2)) * K + (c0 & 3) * 8;
    const _Float16* Wg1 = W + (size_t)(bcol + (c1 >> 2)) * K + (c1 & 3) * 8;
    _Float16* Al0 = As + c0 * 8;
    _Float16* Al1 = As + c1 * 8;
    _Float16* Bl0 = Bs + c0 * 8;
    _Float16* Bl1 = Bs + c1 * 8;

    f32x4 acc[4][4];
#pragma unroll
    for (int i = 0; i < 4; i++)
#pragma unroll
        for (int j = 0; j < 4; j++) acc[i][j] = (f32x4){0.f, 0.f, 0.f, 0.f};

    const int fr = lane & 15;
    const int kq = lane >> 4;
    const int aoff = (wr * 64 + fr) * 32 + kq * 8;
    const int boff = (wc * 64 + fr) * 32 + kq * 8;

    for (int k0 = 0; k0 < K; k0 += 32) {
        __syncthreads();
        gload16(Ag0 + k0, Al0);
        gload16(Ag1 + k0, Al1);
        gload16(Wg0 + k0, Bl0);
        gload16(Wg1 + k0, Bl1);
        __syncthreads();
        f16x8 af[4], bf[4];
#pragma unroll
        for (int mi = 0; mi < 4; mi++) af[mi] = *(const f16x8*)&As[aoff + mi * 512];
#pragma unroll
        for (int ni = 0; ni < 4; ni++) bf[ni] = *(const f16x8*)&Bs[boff + ni * 512];
#pragma unroll
        for (int mi = 0; mi < 4; mi++)
#pragma unroll
            for (int ni = 0; ni < 4; ni++)
                acc[mi][ni] = __builtin_amdgcn_mfma_f32_16x16x32_f16(af[mi], bf[ni], acc[mi][ni], 0, 0, 0);
    }
#pragma unroll
    for (int mi = 0; mi < 4; mi++) {
#pragma unroll
        for (int ni = 0; ni < 4; ni++) {
            const int row = brow + wr * 64 + mi * 16 + kq * 4;
            const int col = bcol + wc * 64 + ni * 16 + fr;
#pragma unroll
            for (int r = 0; r < 4; r++)
                C[(size_t)(row + r) * N + col] = (CT)acc[mi][ni][r];
        }
    }
}

// ---------------- MFMA phi_k + kv/ksum partials; P staged in LDS once ----------------
__global__ __launch_bounds__(256) void kv_kernel2b(const _Float16* __restrict__ k,
                                                   const _Float16* __restrict__ v,
                                                   const int* __restrict__ mask,
                                                   const _Float16* __restrict__ Phs,
                                                   float* __restrict__ kvpart,
                                                   float* __restrict__ kspart) {
    const int bh = blockIdx.y, b = bh >> 4, h = bh & 15;
    const int ch = blockIdx.x;
    const int t = threadIdx.x, lane = t & 63, w = t >> 6;
    const int fr = lane & 15, kq = lane >> 4;

    __shared__ _Float16 phis[256 * 64];   // [m][l] swizzled          32KB
    __shared__ _Float16 vst[80 * 64];     // [d][l] swizzled; row64=1 10KB
    __shared__ _Float16 Pl[256 * 64];     // pre-swizzled P image     32KB

    // ---- stage P once (linear gload from pre-swizzled global) ----
#pragma unroll
    for (int i = 0; i < 8; i++)
        gload16(Phs + (size_t)(t + i * 256) * 8, Pl + (t + i * 256) * 8);

    if (t < 128) {
        const int row = 64 + (t >> 3), off = (t & 7) * 8;
        const _Float16 val = (row == 64) ? (_Float16)1.0f : (_Float16)0.0f;
        f16x8 o = {val, val, val, val, val, val, val, val};
        *(f16x8*)&vst[row * 64 + off] = o;
    }
    __syncthreads();   // Pl staged, vst rows 64.. ready

    f32x4 acc[4][5];
#pragma unroll
    for (int mf = 0; mf < 4; mf++)
#pragma unroll
        for (int n2 = 0; n2 < 5; n2++) acc[mf][n2] = (f32x4){0.f, 0.f, 0.f, 0.f};

    const int rr = t & 31, seg = t >> 5;

    for (int tile = 0; tile < LC / 64; ++tile) {
        const int l0 = ch * LC + tile * 64;

        {
            const _Float16* v0 = v + (size_t)(b * L + l0 + 2 * rr) * D + h * DK + seg * 8;
            f16x8 a0 = *(const f16x8*)v0;
            f16x8 a1 = *(const f16x8*)(v0 + D);
#pragma unroll
            for (int j = 0; j < 8; j++) {
                const int d = seg * 8 + j;
                f16x2 pk = {a0[j], a1[j]};
                *(f16x2*)&vst[SWZ(d, 2 * rr)] = pk;
            }
        }

        const _Float16* krow = k + (size_t)(b * L + l0 + w * 16 + fr) * D + h * DK + kq * 8;
        f16x8 ak0 = *(const f16x8*)krow;
        f16x8 ak1 = *(const f16x8*)(krow + 32);
        float ns = 0.f;
#pragma unroll
        for (int j = 0; j < 8; j++)
            ns += (float)ak0[j] * (float)ak0[j] + (float)ak1[j] * (float)ak1[j];
        ns += __shfl_xor(ns, 16);
        ns += __shfl_xor(ns, 32);
        ns *= HALF_DN2;

        f32x4 pr[16];
#pragma unroll
        for (int nf = 0; nf < 16; nf++) {
            const int rb = (nf * 16 + fr) * 64;     // row&7 == fr&7
            f16x8 b0 = *(const f16x8*)&Pl[rb + ((kq ^ (fr & 7)) << 3)];
            f16x8 b1 = *(const f16x8*)&Pl[rb + (((kq + 4) ^ (fr & 7)) << 3)];
            f32x4 c = {0.f, 0.f, 0.f, 0.f};
            c = __builtin_amdgcn_mfma_f32_16x16x32_f16(ak0, b0, c, 0, 0, 0);
            c = __builtin_amdgcn_mfma_f32_16x16x32_f16(ak1, b1, c, 0, 0, 0);
            pr[nf] = c;
        }
        float mx[4] = {-1e30f, -1e30f, -1e30f, -1e30f};
#pragma unroll
        for (int nf = 0; nf < 16; nf++)
#pragma unroll
            for (int r = 0; r < 4; r++) {
                pr[nf][r] *= DNORM;
                mx[r] = fmaxf(mx[r], pr[nf][r]);
            }
#pragma unroll
        for (int r = 0; r < 4; r++) {
            mx[r] = fmaxf(mx[r], __shfl_xor(mx[r], 1));
            mx[r] = fmaxf(mx[r], __shfl_xor(mx[r], 2));
            mx[r] = fmaxf(mx[r], __shfl_xor(mx[r], 4));
            mx[r] = fmaxf(mx[r], __shfl_xor(mx[r], 8));
        }
        float sub[4], mkv[4];
#pragma unroll
        for (int r = 0; r < 4; r++) {
            sub[r] = mx[r] + __shfl(ns, kq * 4 + r);
            mkv[r] = (float)mask[b * L + l0 + w * 16 + kq * 4 + r];
        }
#pragma unroll
        for (int nf = 0; nf < 16; nf++) {
            const int col = nf * 16 + fr;
#pragma unroll
            for (int rp = 0; rp < 2; rp++) {
                const int row = w * 16 + kq * 4 + 2 * rp;
                float v0 = mkv[2 * rp]     * (RATIO * (__expf(pr[nf][2 * rp]     - sub[2 * rp])     + 1e-6f));
                float v1 = mkv[2 * rp + 1] * (RATIO * (__expf(pr[nf][2 * rp + 1] - sub[2 * rp + 1]) + 1e-6f));
                f16x2 pk = {(_Float16)v0, (_Float16)v1};
                *(f16x2*)&phis[SWZ(col, row)] = pk;
            }
        }
        __syncthreads();

        f16x8 bfr[5][2];
#pragma unroll
        for (int n2 = 0; n2 < 5; n2++)
#pragma unroll
            for (int ks = 0; ks < 2; ks++)
                bfr[n2][ks] = *(const f16x8*)&vst[SWZ(n2 * 16 + fr, ks * 32 + kq * 8)];
#pragma unroll
        for (int mf = 0; mf < 4; mf++) {
            const int m = w * 64 + mf * 16 + fr;
            f16x8 a0 = *(const f16x8*)&phis[SWZ(m, kq * 8)];
            f16x8 a1 = *(const f16x8*)&phis[SWZ(m, 32 + kq * 8)];
#pragma unroll
            for (int n2 = 0; n2 < 5; n2++) {
                acc[mf][n2] = __builtin_amdgcn_mfma_f32_16x16x32_f16(a0, bfr[n2][0], acc[mf][n2], 0, 0, 0);
                acc[mf][n2] = __builtin_amdgcn_mfma_f32_16x16x32_f16(a1, bfr[n2][1], acc[mf][n2], 0, 0, 0);
            }
        }
        __syncthreads();
    }

    float* kvp = kvpart + ((size_t)ch * 64 + bh) * M * DK;
    float* ksp = kspart + ((size_t)ch * 64 + bh) * M;
#pragma unroll
    for (int mf = 0; mf < 4; mf++) {
#pragma unroll
        for (int r = 0; r < 4; r++) {
            const int m = w * 64 + mf * 16 + kq * 4 + r;
#pragma unroll
            for (int n2 = 0; n2 < 4; n2++)
                kvp[(size_t)m * DK + n2 * 16 + fr] = acc[mf][n2][r];
            if (fr == 0) ksp[m] = acc[mf][4][r];
        }
    }
}

// ---------------- reduce partials -> kvt fp16 [bh][80][256], PRE-SWIZZLED ----------------
__global__ __launch_bounds__(256) void reduce_kvt(const float* __restrict__ kvp,
                                                  const float* __restrict__ ksp,
                                                  _Float16* __restrict__ kvt) {
    const int bh = blockIdx.x;
    const int t  = threadIdx.x;   // m index (column)
    float s[64];
#pragma unroll
    for (int c = 0; c < 64; c++) s[c] = 0.f;
    float s64 = 0.f;
    for (int ch = 0; ch < NCH; ch++) {
        const float* src = kvp + (((size_t)ch * 64 + bh) * M + t) * DK;
#pragma unroll
        for (int c4 = 0; c4 < 16; c4++) {
            float4 v = *(const float4*)(src + c4 * 4);
            s[c4 * 4 + 0] += v.x; s[c4 * 4 + 1] += v.y;
            s[c4 * 4 + 2] += v.z; s[c4 * 4 + 3] += v.w;
        }
        s64 += ksp[((size_t)ch * 64 + bh) * M + t];
    }
    _Float16* dst = kvt + (size_t)bh * 80 * 256;
    const int chunk = t >> 3, within = t & 7;
#pragma unroll
    for (int r = 0; r < 64; r++)
        dst[r * 256 + ((chunk ^ (r & 7)) << 3) + within] = (_Float16)s[r];
    dst[64 * 256 + t] = (_Float16)s64;      // row 64: 64&7==0 -> linear
#pragma unroll
    for (int r = 65; r < 80; r++)
        dst[r * 256 + t] = (_Float16)0.f;   // zeros: swizzle-invariant
}

// ---------------- phi_q + out + denom + normalize; kvt+P staged once per 256 rows ----------------
// grid (L/256, B*H) = (16,16), block 256 (4 waves), 4 row-tiles of 64.
__global__ __launch_bounds__(256) void out_kernel4(const _Float16* __restrict__ q,
                                                   const _Float16* __restrict__ Phs,
                                                   const _Float16* __restrict__ kvtg,
                                                   _Float16* __restrict__ ao) {
    const int bh = blockIdx.y, b = bh >> 4, h = bh & 15;
    const int t = threadIdx.x, lane = t & 63, w = t >> 6;
    const int fr = lane & 15, kq = lane >> 4;

    __shared__ _Float16 Pl[256 * 64];     // pre-swizzled P      32KB
    __shared__ _Float16 kvs[80 * 256];    // pre-swizzled kvt    40KB
    __shared__ _Float16 phis[64 * 256];   // [l][m] swizzled     32KB

    // ---- stage P + kvt once ----
#pragma unroll
    for (int i = 0; i < 8; i++)
        gload16(Phs + (size_t)(t + i * 256) * 8, Pl + (t + i * 256) * 8);
    {
        const _Float16* src = kvtg + (size_t)bh * 80 * 256 + t * 8;
#pragma unroll
        for (int i = 0; i < 10; i++)
            gload16(src + i * 2048, kvs + t * 8 + i * 2048);
    }
    __syncthreads();

    for (int rt = 0; rt < 4; ++rt) {
        const int l0 = blockIdx.x * 256 + rt * 64;

        // ---- q fragments direct from global + row norm ----
        const _Float16* qp = q + (size_t)(b * L + l0 + w * 16 + fr) * D + h * DK + kq * 8;
        f16x8 aq0 = *(const f16x8*)qp;
        f16x8 aq1 = *(const f16x8*)(qp + 32);
        float ns = 0.f;
#pragma unroll
        for (int j = 0; j < 8; j++)
            ns += (float)aq0[j] * (float)aq0[j] + (float)aq1[j] * (float)aq1[j];
        ns += __shfl_xor(ns, 16);
        ns += __shfl_xor(ns, 32);
        ns *= HALF_DN2;

        // ---- phase 1: proj = q @ P^T (P from LDS) ----
        f32x4 pr[16];
#pragma unroll
        for (int nf = 0; nf < 16; nf++) {
            const int rb = (nf * 16 + fr) * 64;     // row&7 == fr&7
            f16x8 b0 = *(const f16x8*)&Pl[rb + ((kq ^ (fr & 7)) << 3)];
            f16x8 b1 = *(const f16x8*)&Pl[rb + (((kq + 4) ^ (fr & 7)) << 3)];
            f32x4 c = {0.f, 0.f, 0.f, 0.f};
            c = __builtin_amdgcn_mfma_f32_16x16x32_f16(aq0, b0, c, 0, 0, 0);
            c = __builtin_amdgcn_mfma_f32_16x16x32_f16(aq1, b1, c, 0, 0, 0);
            pr[nf] = c;
        }
        float mx[4] = {-1e30f, -1e30f, -1e30f, -1e30f};
#pragma unroll
        for (int nf = 0; nf < 16; nf++)
#pragma unroll
            for (int r = 0; r < 4; r++) {
                pr[nf][r] *= DNORM;
                mx[r] = fmaxf(mx[r], pr[nf][r]);
            }
#pragma unroll
        for (int r = 0; r < 4; r++) {
            mx[r] = fmaxf(mx[r], __shfl_xor(mx[r], 1));
            mx[r] = fmaxf(mx[r], __shfl_xor(mx[r], 2));
            mx[r] = fmaxf(mx[r], __shfl_xor(mx[r], 4));
            mx[r] = fmaxf(mx[r], __shfl_xor(mx[r], 8));
        }
        float sub[4];
#pragma unroll
        for (int r = 0; r < 4; r++) sub[r] = mx[r] + __shfl(ns, kq * 4 + r);
        // phi -> swizzled LDS
#pragma unroll
        for (int nf = 0; nf < 16; nf++) {
            const int cch = nf * 2 + (fr >> 3), cw = fr & 7;
#pragma unroll
            for (int r = 0; r < 4; r++) {
                const int row = w * 16 + kq * 4 + r;
                float val = RATIO * (__expf(pr[nf][r] - sub[r]) + 1e-6f);
                phis[row * 256 + ((cch ^ (row & 7)) << 3) + cw] = (_Float16)val;
            }
        }
        __syncthreads();

        // ---- phase 2: out[64][80] = phi @ kvs^T (row 64 = denom) ----
        f32x4 acc[5];
#pragma unroll
        for (int n2 = 0; n2 < 5; n2++) acc[n2] = (f32x4){0.f, 0.f, 0.f, 0.f};
        const int arow = w * 16 + fr;
#pragma unroll
        for (int ks = 0; ks < 8; ks++) {
            const int c = ks * 4 + kq;
            f16x8 af = *(const f16x8*)&phis[arow * 256 + ((c ^ (arow & 7)) << 3)];
#pragma unroll
            for (int n2 = 0; n2 < 5; n2++) {
                const int n = n2 * 16 + fr;
                f16x8 bf = *(const f16x8*)&kvs[n * 256 + ((c ^ (n & 7)) << 3)];
                acc[n2] = __builtin_amdgcn_mfma_f32_16x16x32_f16(af, bf, acc[n2], 0, 0, 0);
            }
        }
        // ---- normalize + write ----
#pragma unroll
        for (int r = 0; r < 4; r++) {
            float den = __shfl(acc[4][r], (lane & 48));
            float inv = 1.f / fmaxf(den, 1e-6f);
            const int row = l0 + w * 16 + kq * 4 + r;
            _Float16* dst = ao + (size_t)(b * L + row) * D + h * DK;
#pragma unroll
            for (int n2 = 0; n2 < 4; n2++)
                dst[n2 * 16 + fr] = (_Float16)(acc[n2][r] * inv);
        }
        __syncthreads();   // protect phis before next tile overwrites
    }
}

extern "C" void kernel_launch(void* const* d_in, const int* in_sizes, int n_in,
                              void* d_out, int out_size, void* d_ws, size_t ws_size,
                              hipStream_t stream) {
    (void)in_sizes; (void)n_in; (void)out_size; (void)ws_size;
    const float* X    = (const float*)d_in[0];
    const int*   mask = (const int*)d_in[1];
    const float* Wq   = (const float*)d_in[2];
    const float* Wk   = (const float*)d_in[3];
    const float* Wv   = (const float*)d_in[4];
    const float* Wo   = (const float*)d_in[5];
    const float* P    = (const float*)d_in[6];

    char* ws = (char*)d_ws;
    _Float16* bufK  = (_Float16*)ws;                      // k, later attn (32MB)
    _Float16* bufVQ = (_Float16*)(ws + 33554432);         // v, later q    (32MB)
    float* kvpart   = (float*)(ws + 67108864);            // 32MB
    float* kspart   = (float*)(ws + 100663296);           // 512KB
    _Float16* kvt   = (_Float16*)(ws + 101187584);        // 2.62MB
    _Float16* Xh    = (_Float16*)(ws + 103809024);        // 32MB
    _Float16* Wkh   = (_Float16*)(ws + 137363456);        // 2MB
    _Float16* Wvh   = (_Float16*)(ws + 139460608);        // 2MB
    _Float16* Wqh   = (_Float16*)(ws + 141557760);        // 2MB
    _Float16* Woh   = (_Float16*)(ws + 143654912);        // 2MB
    _Float16* Phs   = (_Float16*)(ws + 145752064);        // 32KB (pre-swizzled P)
    float* out      = (float*)d_out;

    dim3 blk(256);
    hipLaunchKernelGGL(cast_f32_f16, dim3(8192), blk, 0, stream, X, Xh, 2097152);
    hipLaunchKernelGGL(cast_f32_f16, dim3(512), blk, 0, stream, Wk, Wkh, 131072);
    hipLaunchKernelGGL(cast_f32_f16, dim3(512), blk, 0, stream, Wv, Wvh, 131072);
    hipLaunchKernelGGL(cast_f32_f16, dim3(512), blk, 0, stream, Wq, Wqh, 131072);
    hipLaunchKernelGGL(cast_f32_f16, dim3(512), blk, 0, stream, Wo, Woh, 131072);
    hipLaunchKernelGGL(cast_P_swz, dim3(1), blk, 0, stream, P, Phs);

    dim3 gg(8, 128);
    hipLaunchKernelGGL((gemm_f16<_Float16>), gg, blk, 0, stream, Xh, Wkh, bufK, D, D);
    hipLaunchKernelGGL((gemm_f16<_Float16>), gg, blk, 0, stream, Xh, Wvh, bufVQ, D, D);
    hipLaunchKernelGGL(kv_kernel2b, dim3(NCH, B * H), blk, 0, stream, bufK, bufVQ, mask, Phs, kvpart, kspart);
    hipLaunchKernelGGL(reduce_kvt, dim3(64), blk, 0, stream, kvpart, kspart, kvt);
    hipLaunchKernelGGL((gemm_f16<_Float16>), gg, blk, 0, stream, Xh, Wqh, bufVQ, D, D);
    hipLaunchKernelGGL(out_kernel4, dim3(L / 256, B * H), blk, 0, stream, bufVQ, Phs, kvt, bufK);
    hipLaunchKernelGGL((gemm_f16<float>), gg, blk, 0, stream, bufK, Woh, out, D, D);
}

// Round 7
// 424.791 us; speedup vs baseline: 9.2750x; 1.0026x over previous
//
#include <hip/hip_runtime.h>
#include <math.h>

#define B 4
#define L 4096
#define D 1024
#define H 16
#define DK 64
#define M 256
#define NTOK (B*L)        // 16384
#define NCH 8
#define LC (L/NCH)        // 512

// dn = 64^-0.25 = 2^-1.5 ; dn^2*0.5 = 0.0625 ; ratio = 256^-0.5 = 0.0625
#define DNORM 0.35355339059327373f
#define HALF_DN2 0.0625f
#define RATIO 0.0625f

typedef _Float16 f16x8 __attribute__((ext_vector_type(8)));
typedef _Float16 f16x2 __attribute__((ext_vector_type(2)));
typedef float f32x4 __attribute__((ext_vector_type(4)));
typedef unsigned u32x4 __attribute__((ext_vector_type(4)));

// XOR-swizzled LDS index for [col][64 l] fp16 tiles: 8-half blocks permuted by col&7
#define SWZ(col, l) ((col) * 64 + (((l) & 7) | ((((((l) >> 3)) ^ (col)) & 7) << 3)))

__device__ __forceinline__ void gload16(const void* g, void* l) {
    __builtin_amdgcn_global_load_lds((const __attribute__((address_space(1))) unsigned*)g,
                                     (__attribute__((address_space(3))) unsigned*)l, 16, 0, 0);
}

// ---------------- fp32 -> fp16 cast (8 elems/thread) ----------------
__global__ __launch_bounds__(256) void cast_f32_f16(const float* __restrict__ in,
                                                    _Float16* __restrict__ out, int n8) {
    int i = blockIdx.x * 256 + threadIdx.x;
    if (i >= n8) return;
    const float4* p = (const float4*)(in + (size_t)i * 8);
    float4 a = p[0], b = p[1];
    f16x8 o;
    o[0] = (_Float16)a.x; o[1] = (_Float16)a.y; o[2] = (_Float16)a.z; o[3] = (_Float16)a.w;
    o[4] = (_Float16)b.x; o[5] = (_Float16)b.y; o[6] = (_Float16)b.z; o[7] = (_Float16)b.w;
    *(f16x8*)(out + (size_t)i * 8) = o;
}

// ---------------- P fp32 [256][64] -> fp16 FRAGMENT-LINEAR image ----------------
// chunk c = (nf*2+kh)*64 + lane, lane=(kq*16+fr): holds P[nf*16+fr][kh*32+kq*8 + j], j=0..7
__global__ __launch_bounds__(256) void cast_P_frag(const float* __restrict__ P,
                                                   _Float16* __restrict__ Phf) {
    const int t = threadIdx.x;
#pragma unroll
    for (int i = 0; i < 8; i++) {
        const int c = t + i * 256;
        const int f = c >> 6, lane2 = c & 63;
        const int nf = f >> 1, kh = f & 1;
        const int fr = lane2 & 15, kq2 = lane2 >> 4;
        const float* src = P + (nf * 16 + fr) * 64 + kh * 32 + kq2 * 8;
        f16x8 o;
#pragma unroll
        for (int j = 0; j < 8; j++) o[j] = (_Float16)src[j];
        *(f16x8*)(Phf + (size_t)c * 8) = o;
    }
}

// ---------------- fp16 MFMA GEMM:  C[n][o] = sum_k A[n][k] * W[o][k] ----------------
template <typename CT>
__global__ __launch_bounds__(256) void gemm_f16(const _Float16* __restrict__ A,
                                                const _Float16* __restrict__ W,
                                                CT* __restrict__ C,
                                                int N, int K) {
    __shared__ _Float16 As[128 * 32];
    __shared__ _Float16 Bs[128 * 32];
    const int t    = threadIdx.x;
    const int lane = t & 63;
    const int w    = t >> 6;
    const int wr   = w >> 1, wc = w & 1;
    const int brow = blockIdx.y * 128, bcol = blockIdx.x * 128;

    const int c0 = t, c1 = t + 256;
    const _Float16* Ag0 = A + (size_t)(brow + (c0 >> 2)) * K + (c0 & 3) * 8;
    const _Float16* Ag1 = A + (size_t)(brow + (c1 >> 2)) * K + (c1 & 3) * 8;
    const _Float16* Wg0 = W + (size_t)(bcol + (c0 >> 2)) * K + (c0 & 3) * 8;
    const _Float16* Wg1 = W + (size_t)(bcol + (c1 >> 2)) * K + (c1 & 3) * 8;
    _Float16* Al0 = As + c0 * 8;
    _Float16* Al1 = As + c1 * 8;
    _Float16* Bl0 = Bs + c0 * 8;
    _Float16* Bl1 = Bs + c1 * 8;

    f32x4 acc[4][4];
#pragma unroll
    for (int i = 0; i < 4; i++)
#pragma unroll
        for (int j = 0; j < 4; j++) acc[i][j] = (f32x4){0.f, 0.f, 0.f, 0.f};

    const int fr = lane & 15;
    const int kq = lane >> 4;
    const int aoff = (wr * 64 + fr) * 32 + kq * 8;
    const int boff = (wc * 64 + fr) * 32 + kq * 8;

    for (int k0 = 0; k0 < K; k0 += 32) {
        __syncthreads();
        gload16(Ag0 + k0, Al0);
        gload16(Ag1 + k0, Al1);
        gload16(Wg0 + k0, Bl0);
        gload16(Wg1 + k0, Bl1);
        __syncthreads();
        f16x8 af[4], bf[4];
#pragma unroll
        for (int mi = 0; mi < 4; mi++) af[mi] = *(const f16x8*)&As[aoff + mi * 512];
#pragma unroll
        for (int ni = 0; ni < 4; ni++) bf[ni] = *(const f16x8*)&Bs[boff + ni * 512];
#pragma unroll
        for (int mi = 0; mi < 4; mi++)
#pragma unroll
            for (int ni = 0; ni < 4; ni++)
                acc[mi][ni] = __builtin_amdgcn_mfma_f32_16x16x32_f16(af[mi], bf[ni], acc[mi][ni], 0, 0, 0);
    }
#pragma unroll
    for (int mi = 0; mi < 4; mi++) {
#pragma unroll
        for (int ni = 0; ni < 4; ni++) {
            const int row = brow + wr * 64 + mi * 16 + kq * 4;
            const int col = bcol + wc * 64 + ni * 16 + fr;
#pragma unroll
            for (int r = 0; r < 4; r++)
                C[(size_t)(row + r) * N + col] = (CT)acc[mi][ni][r];
        }
    }
}

// ---------------- MFMA phi_k + kv/ksum partials; P staged in LDS once ----------------
__global__ __launch_bounds__(256) void kv_kernel2b(const _Float16* __restrict__ k,
                                                   const _Float16* __restrict__ v,
                                                   const int* __restrict__ mask,
                                                   const _Float16* __restrict__ Phf,
                                                   float* __restrict__ kvpart,
                                                   float* __restrict__ kspart) {
    const int bh = blockIdx.y, b = bh >> 4, h = bh & 15;
    const int ch = blockIdx.x;
    const int t = threadIdx.x, lane = t & 63, w = t >> 6;
    const int fr = lane & 15, kq = lane >> 4;

    __shared__ _Float16 phis[256 * 64];   // [m][l] swizzled          32KB
    __shared__ _Float16 vst[80 * 64];     // [d][l] swizzled; row64=1 10KB
    __shared__ _Float16 Pl[256 * 64];     // fragment-linear P image  32KB

    // ---- stage P once (linear gload from frag-linear global) ----
#pragma unroll
    for (int i = 0; i < 8; i++)
        gload16(Phf + (size_t)(t + i * 256) * 8, Pl + (t + i * 256) * 8);

    if (t < 128) {
        const int row = 64 + (t >> 3), off = (t & 7) * 8;
        const _Float16 val = (row == 64) ? (_Float16)1.0f : (_Float16)0.0f;
        f16x8 o = {val, val, val, val, val, val, val, val};
        *(f16x8*)&vst[row * 64 + off] = o;
    }
    __syncthreads();   // Pl staged, vst rows 64.. ready

    f32x4 acc[4][5];
#pragma unroll
    for (int mf = 0; mf < 4; mf++)
#pragma unroll
        for (int n2 = 0; n2 < 5; n2++) acc[mf][n2] = (f32x4){0.f, 0.f, 0.f, 0.f};

    const int rr = t & 31, seg = t >> 5;

    for (int tile = 0; tile < LC / 64; ++tile) {
        const int l0 = ch * LC + tile * 64;

        {
            const _Float16* v0 = v + (size_t)(b * L + l0 + 2 * rr) * D + h * DK + seg * 8;
            f16x8 a0 = *(const f16x8*)v0;
            f16x8 a1 = *(const f16x8*)(v0 + D);
#pragma unroll
            for (int j = 0; j < 8; j++) {
                const int d = seg * 8 + j;
                f16x2 pk = {a0[j], a1[j]};
                *(f16x2*)&vst[SWZ(d, 2 * rr)] = pk;
            }
        }

        const _Float16* krow = k + (size_t)(b * L + l0 + w * 16 + fr) * D + h * DK + kq * 8;
        f16x8 ak0 = *(const f16x8*)krow;
        f16x8 ak1 = *(const f16x8*)(krow + 32);
        float ns = 0.f;
#pragma unroll
        for (int j = 0; j < 8; j++)
            ns += (float)ak0[j] * (float)ak0[j] + (float)ak1[j] * (float)ak1[j];
        ns += __shfl_xor(ns, 16);
        ns += __shfl_xor(ns, 32);
        ns *= HALF_DN2;

        f32x4 pr[16];
#pragma unroll
        for (int nf = 0; nf < 16; nf++) {
            f16x8 b0 = *(const f16x8*)&Pl[((nf * 2 + 0) * 64 + lane) * 8];
            f16x8 b1 = *(const f16x8*)&Pl[((nf * 2 + 1) * 64 + lane) * 8];
            f32x4 c = {0.f, 0.f, 0.f, 0.f};
            c = __builtin_amdgcn_mfma_f32_16x16x32_f16(ak0, b0, c, 0, 0, 0);
            c = __builtin_amdgcn_mfma_f32_16x16x32_f16(ak1, b1, c, 0, 0, 0);
            pr[nf] = c;
        }
        float mx[4] = {-1e30f, -1e30f, -1e30f, -1e30f};
#pragma unroll
        for (int nf = 0; nf < 16; nf++)
#pragma unroll
            for (int r = 0; r < 4; r++) {
                pr[nf][r] *= DNORM;
                mx[r] = fmaxf(mx[r], pr[nf][r]);
            }
#pragma unroll
        for (int r = 0; r < 4; r++) {
            mx[r] = fmaxf(mx[r], __shfl_xor(mx[r], 1));
            mx[r] = fmaxf(mx[r], __shfl_xor(mx[r], 2));
            mx[r] = fmaxf(mx[r], __shfl_xor(mx[r], 4));
            mx[r] = fmaxf(mx[r], __shfl_xor(mx[r], 8));
        }
        float sub[4], mkv[4];
#pragma unroll
        for (int r = 0; r < 4; r++) {
            sub[r] = mx[r] + __shfl(ns, kq * 4 + r);
            mkv[r] = (float)mask[b * L + l0 + w * 16 + kq * 4 + r];
        }
#pragma unroll
        for (int nf = 0; nf < 16; nf++) {
            const int col = nf * 16 + fr;
#pragma unroll
            for (int rp = 0; rp < 2; rp++) {
                const int row = w * 16 + kq * 4 + 2 * rp;
                float v0 = mkv[2 * rp]     * (RATIO * (__expf(pr[nf][2 * rp]     - sub[2 * rp])     + 1e-6f));
                float v1 = mkv[2 * rp + 1] * (RATIO * (__expf(pr[nf][2 * rp + 1] - sub[2 * rp + 1]) + 1e-6f));
                f16x2 pk = {(_Float16)v0, (_Float16)v1};
                *(f16x2*)&phis[SWZ(col, row)] = pk;
            }
        }
        __syncthreads();

        f16x8 bfr[5][2];
#pragma unroll
        for (int n2 = 0; n2 < 5; n2++)
#pragma unroll
            for (int ks = 0; ks < 2; ks++)
                bfr[n2][ks] = *(const f16x8*)&vst[SWZ(n2 * 16 + fr, ks * 32 + kq * 8)];
#pragma unroll
        for (int mf = 0; mf < 4; mf++) {
            const int m = w * 64 + mf * 16 + fr;
            f16x8 a0 = *(const f16x8*)&phis[SWZ(m, kq * 8)];
            f16x8 a1 = *(const f16x8*)&phis[SWZ(m, 32 + kq * 8)];
#pragma unroll
            for (int n2 = 0; n2 < 5; n2++) {
                acc[mf][n2] = __builtin_amdgcn_mfma_f32_16x16x32_f16(a0, bfr[n2][0], acc[mf][n2], 0, 0, 0);
                acc[mf][n2] = __builtin_amdgcn_mfma_f32_16x16x32_f16(a1, bfr[n2][1], acc[mf][n2], 0, 0, 0);
            }
        }
        __syncthreads();
    }

    float* kvp = kvpart + ((size_t)ch * 64 + bh) * M * DK;
    float* ksp = kspart + ((size_t)ch * 64 + bh) * M;
#pragma unroll
    for (int mf = 0; mf < 4; mf++) {
#pragma unroll
        for (int r = 0; r < 4; r++) {
            const int m = w * 64 + mf * 16 + kq * 4 + r;
#pragma unroll
            for (int n2 = 0; n2 < 4; n2++)
                kvp[(size_t)m * DK + n2 * 16 + fr] = acc[mf][n2][r];
            if (fr == 0) ksp[m] = acc[mf][4][r];
        }
    }
}

// ---------------- reduce partials -> kvt fp16 FRAGMENT-LINEAR [bh][(n2*8+ks)*64+lane][8] ----------------
// value[d = n2*16+fr][m = ks*32+kq*8+j]; n2=4: fr=0 -> ksum, fr>0 -> 0
__global__ __launch_bounds__(256) void reduce_kvt(const float* __restrict__ kvp,
                                                  const float* __restrict__ ksp,
                                                  _Float16* __restrict__ kvt) {
    const int bh = blockIdx.x;
    const int t  = threadIdx.x;   // m index
    float s[64];
#pragma unroll
    for (int c = 0; c < 64; c++) s[c] = 0.f;
    float s64 = 0.f;
    for (int ch = 0; ch < NCH; ch++) {
        const float* src = kvp + (((size_t)ch * 64 + bh) * M + t) * DK;
#pragma unroll
        for (int c4 = 0; c4 < 16; c4++) {
            float4 v = *(const float4*)(src + c4 * 4);
            s[c4 * 4 + 0] += v.x; s[c4 * 4 + 1] += v.y;
            s[c4 * 4 + 2] += v.z; s[c4 * 4 + 3] += v.w;
        }
        s64 += ksp[((size_t)ch * 64 + bh) * M + t];
    }
    _Float16* dst = kvt + (size_t)bh * 20480;
    const int ks = t >> 5, kq = (t >> 3) & 3, j = t & 7;
#pragma unroll
    for (int d = 0; d < 64; d++) {
        const int n2 = d >> 4, fr = d & 15;
        dst[((n2 * 8 + ks) * 64 + kq * 16 + fr) * 8 + j] = (_Float16)s[d];
    }
    dst[((4 * 8 + ks) * 64 + kq * 16 + 0) * 8 + j] = (_Float16)s64;
#pragma unroll
    for (int fr = 1; fr < 16; fr++)
        dst[((4 * 8 + ks) * 64 + kq * 16 + fr) * 8 + j] = (_Float16)0.f;
}

// ---------------- phi_q + out + denom + normalize; swapped QK, register butterfly ----------------
// grid (L/256, B*H), block 256 (4 waves), 4 row-tiles of 64. LDS: P 32K + kvs 40K = 72K.
__global__ __launch_bounds__(256) void out_kernel5(const _Float16* __restrict__ q,
                                                   const _Float16* __restrict__ Phf,
                                                   const _Float16* __restrict__ kvtf,
                                                   _Float16* __restrict__ ao) {
    const int bh = blockIdx.y, b = bh >> 4, h = bh & 15;
    const int t = threadIdx.x, lane = t & 63, w = t >> 6;
    const int fr = lane & 15, kq = lane >> 4;

    __shared__ _Float16 Pl[2048 * 8];     // fragment-linear P    32KB
    __shared__ _Float16 kvs[2560 * 8];    // fragment-linear kvt  40KB

    // ---- stage P + kvt once (both frag-linear in global -> linear gload_lds) ----
#pragma unroll
    for (int i = 0; i < 8; i++)
        gload16(Phf + (size_t)(t + i * 256) * 8, Pl + (t + i * 256) * 8);
    {
        const _Float16* src = kvtf + (size_t)bh * 20480 + t * 8;
#pragma unroll
        for (int i = 0; i < 10; i++)
            gload16(src + i * 2048, kvs + t * 8 + i * 2048);
    }
    __syncthreads();

    const int srcA = fr + 16 * ((2 * kq) & 3);
    const int srcB = fr + 16 * ((2 * kq + 1) & 3);
    const bool hi  = (kq & 2) != 0;

    for (int rt = 0; rt < 4; ++rt) {
        const int l0 = blockIdx.x * 256 + rt * 64;

        // ---- q fragment (B operand) direct from global + row norm (lane-local in l=w*16+fr) ----
        const _Float16* qp = q + (size_t)(b * L + l0 + w * 16 + fr) * D + h * DK + kq * 8;
        f16x8 aq0 = *(const f16x8*)qp;
        f16x8 aq1 = *(const f16x8*)(qp + 32);
        float ns = 0.f;
#pragma unroll
        for (int j = 0; j < 8; j++)
            ns += (float)aq0[j] * (float)aq0[j] + (float)aq1[j] * (float)aq1[j];
        ns += __shfl_xor(ns, 16);
        ns += __shfl_xor(ns, 32);
        ns *= HALF_DN2;

        // ---- phase 1 (swapped): pr[nf] = P(nf-tile) x q -> C[m][l], col l = fr ----
        f32x4 pr[16];
#pragma unroll
        for (int nf = 0; nf < 16; nf++) {
            f16x8 a0 = *(const f16x8*)&Pl[((nf * 2 + 0) * 64 + lane) * 8];
            f16x8 a1 = *(const f16x8*)&Pl[((nf * 2 + 1) * 64 + lane) * 8];
            f32x4 c = {0.f, 0.f, 0.f, 0.f};
            c = __builtin_amdgcn_mfma_f32_16x16x32_f16(a0, aq0, c, 0, 0, 0);
            c = __builtin_amdgcn_mfma_f32_16x16x32_f16(a1, aq1, c, 0, 0, 0);
            pr[nf] = c;
        }
        // all 64 in-lane values share l -> scalar max
        float mx = -1e30f;
#pragma unroll
        for (int nf = 0; nf < 16; nf++)
#pragma unroll
            for (int r = 0; r < 4; r++) {
                pr[nf][r] *= DNORM;
                mx = fmaxf(mx, pr[nf][r]);
            }
        mx = fmaxf(mx, __shfl_xor(mx, 16));
        mx = fmaxf(mx, __shfl_xor(mx, 32));
        const float sub = mx + ns;

        // ---- phi + pack to f16x2 (in-register, no LDS) ----
        unsigned pk_[16][2];
#pragma unroll
        for (int nf = 0; nf < 16; nf++) {
#pragma unroll
            for (int p = 0; p < 2; p++) {
                float v0 = RATIO * (__expf(pr[nf][2 * p]     - sub) + 1e-6f);
                float v1 = RATIO * (__expf(pr[nf][2 * p + 1] - sub) + 1e-6f);
                f16x2 pq = {(_Float16)v0, (_Float16)v1};
                pk_[nf][p] = __builtin_bit_cast(unsigned, pq);
            }
        }

        // ---- phase 2: out[l][d] = phi @ kv^T ; A-frags via butterfly shuffles ----
        f32x4 acc[5];
#pragma unroll
        for (int n2 = 0; n2 < 5; n2++) acc[n2] = (f32x4){0.f, 0.f, 0.f, 0.f};
#pragma unroll
        for (int ks = 0; ks < 8; ks++) {
            unsigned u0 = __shfl(pk_[2 * ks][0], srcA);
            unsigned u1 = __shfl(pk_[2 * ks][1], srcA);
            unsigned u2 = __shfl(pk_[2 * ks][0], srcB);
            unsigned u3 = __shfl(pk_[2 * ks][1], srcB);
            unsigned v0 = __shfl(pk_[2 * ks + 1][0], srcA);
            unsigned v1 = __shfl(pk_[2 * ks + 1][1], srcA);
            unsigned v2 = __shfl(pk_[2 * ks + 1][0], srcB);
            unsigned v3 = __shfl(pk_[2 * ks + 1][1], srcB);
            u32x4 wv;
            wv[0] = hi ? v0 : u0;
            wv[1] = hi ? v1 : u1;
            wv[2] = hi ? v2 : u2;
            wv[3] = hi ? v3 : u3;
            f16x8 af = __builtin_bit_cast(f16x8, wv);
#pragma unroll
            for (int n2 = 0; n2 < 5; n2++) {
                f16x8 bf = *(const f16x8*)&kvs[((n2 * 8 + ks) * 64 + lane) * 8];
                acc[n2] = __builtin_amdgcn_mfma_f32_16x16x32_f16(af, bf, acc[n2], 0, 0, 0);
            }
        }
        // ---- normalize + write (C layout: row l = w*16+kq*4+r, col d = n2*16+fr) ----
#pragma unroll
        for (int r = 0; r < 4; r++) {
            float den = __shfl(acc[4][r], (lane & 48));
            float inv = 1.f / fmaxf(den, 1e-6f);
            const int row = l0 + w * 16 + kq * 4 + r;
            _Float16* dst = ao + (size_t)(b * L + row) * D + h * DK;
#pragma unroll
            for (int n2 = 0; n2 < 4; n2++)
                dst[n2 * 16 + fr] = (_Float16)(acc[n2][r] * inv);
        }
    }
}

extern "C" void kernel_launch(void* const* d_in, const int* in_sizes, int n_in,
                              void* d_out, int out_size, void* d_ws, size_t ws_size,
                              hipStream_t stream) {
    (void)in_sizes; (void)n_in; (void)out_size; (void)ws_size;
    const float* X    = (const float*)d_in[0];
    const int*   mask = (const int*)d_in[1];
    const float* Wq   = (const float*)d_in[2];
    const float* Wk   = (const float*)d_in[3];
    const float* Wv   = (const float*)d_in[4];
    const float* Wo   = (const float*)d_in[5];
    const float* P    = (const float*)d_in[6];

    char* ws = (char*)d_ws;
    _Float16* bufK  = (_Float16*)ws;                      // k, later attn (32MB)
    _Float16* bufVQ = (_Float16*)(ws + 33554432);         // v, later q    (32MB)
    float* kvpart   = (float*)(ws + 67108864);            // 32MB
    float* kspart   = (float*)(ws + 100663296);           // 512KB
    _Float16* kvt   = (_Float16*)(ws + 101187584);        // 2.62MB
    _Float16* Xh    = (_Float16*)(ws + 103809024);        // 32MB
    _Float16* Wkh   = (_Float16*)(ws + 137363456);        // 2MB
    _Float16* Wvh   = (_Float16*)(ws + 139460608);        // 2MB
    _Float16* Wqh   = (_Float16*)(ws + 141557760);        // 2MB
    _Float16* Woh   = (_Float16*)(ws + 143654912);        // 2MB
    _Float16* Phf   = (_Float16*)(ws + 145752064);        // 32KB (frag-linear P)
    float* out      = (float*)d_out;

    dim3 blk(256);
    hipLaunchKernelGGL(cast_f32_f16, dim3(8192), blk, 0, stream, X, Xh, 2097152);
    hipLaunchKernelGGL(cast_f32_f16, dim3(512), blk, 0, stream, Wk, Wkh, 131072);
    hipLaunchKernelGGL(cast_f32_f16, dim3(512), blk, 0, stream, Wv, Wvh, 131072);
    hipLaunchKernelGGL(cast_f32_f16, dim3(512), blk, 0, stream, Wq, Wqh, 131072);
    hipLaunchKernelGGL(cast_f32_f16, dim3(512), blk, 0, stream, Wo, Woh, 131072);
    hipLaunchKernelGGL(cast_P_frag, dim3(1), blk, 0, stream, P, Phf);

    dim3 gg(8, 128);
    hipLaunchKernelGGL((gemm_f16<_Float16>), gg, blk, 0, stream, Xh, Wkh, bufK, D, D);
    hipLaunchKernelGGL((gemm_f16<_Float16>), gg, blk, 0, stream, Xh, Wvh, bufVQ, D, D);
    hipLaunchKernelGGL(kv_kernel2b, dim3(NCH, B * H), blk, 0, stream, bufK, bufVQ, mask, Phf, kvpart, kspart);
    hipLaunchKernelGGL(reduce_kvt, dim3(64), blk, 0, stream, kvpart, kspart, kvt);
    hipLaunchKernelGGL((gemm_f16<_Float16>), gg, blk, 0, stream, Xh, Wqh, bufVQ, D, D);
    hipLaunchKernelGGL(out_kernel5, dim3(L / 256, B * H), blk, 0, stream, bufVQ, Phf, kvt, bufK);
    hipLaunchKernelGGL((gemm_f16<float>), gg, blk, 0, stream, bufK, Woh, out, D, D);
}